// Round 2
// baseline (3667.508 us; speedup 1.0000x reference)
//
#include <hip/hip_runtime.h>
#include <math.h>

// Problem constants (Decoder_88871463288984)
#define NL 6
#define NH 8
#define MD 1024
#define HD 128
#define FF 4096
#define NB 4
#define NQ 1024
#define NT 1024
#define ROWS (NB*NQ)   // 4096

typedef __attribute__((ext_vector_type(8))) short bf16x8;
typedef __attribute__((ext_vector_type(4))) float f32x4;

// fp32 -> bf16, round-to-nearest-even
__device__ __forceinline__ unsigned short f2bf(float f) {
    unsigned int u = __float_as_uint(f);
    u += 0x7fffu + ((u >> 16) & 1u);
    return (unsigned short)(u >> 16);
}

// async global->LDS, 16 bytes per lane (dst must be wave-uniform base + lane*16)
__device__ __forceinline__ void load16_lds(const unsigned short* g, unsigned short* l) {
    __builtin_amdgcn_global_load_lds(
        (const __attribute__((address_space(1))) unsigned int*)g,
        (__attribute__((address_space(3))) unsigned int*)l, 16, 0, 0);
}

// ---------------------------------------------------------------------------
// LayerNorm: fp32 in (h), bf16 out. One block per row of 1024.
// ---------------------------------------------------------------------------
__global__ __launch_bounds__(256) void ln_kernel(
    const float* __restrict__ x, unsigned short* __restrict__ y,
    const float* __restrict__ g, const float* __restrict__ b)
{
    __shared__ float sdata[8];
    int row = blockIdx.x;
    int tid = threadIdx.x;
    const float* xr = x + (size_t)row * MD;
    float4 v = ((const float4*)xr)[tid];
    float s = v.x + v.y + v.z + v.w;
    #pragma unroll
    for (int o = 32; o > 0; o >>= 1) s += __shfl_down(s, o, 64);
    if ((tid & 63) == 0) sdata[tid >> 6] = s;
    __syncthreads();
    if (tid == 0) sdata[4] = sdata[0] + sdata[1] + sdata[2] + sdata[3];
    __syncthreads();
    float mean = sdata[4] * (1.0f / MD);
    float4 d = make_float4(v.x - mean, v.y - mean, v.z - mean, v.w - mean);
    float sq = d.x*d.x + d.y*d.y + d.z*d.z + d.w*d.w;
    #pragma unroll
    for (int o = 32; o > 0; o >>= 1) sq += __shfl_down(sq, o, 64);
    __syncthreads();
    if ((tid & 63) == 0) sdata[tid >> 6] = sq;
    __syncthreads();
    if (tid == 0) sdata[4] = sdata[0] + sdata[1] + sdata[2] + sdata[3];
    __syncthreads();
    float var = sdata[4] * (1.0f / MD);
    float rstd = rsqrtf(var + 1e-5f);
    float4 g4 = ((const float4*)g)[tid];
    float4 b4 = ((const float4*)b)[tid];
    ushort4 o;
    o.x = f2bf(d.x * rstd * g4.x + b4.x);
    o.y = f2bf(d.y * rstd * g4.y + b4.y);
    o.z = f2bf(d.z * rstd * g4.z + b4.z);
    o.w = f2bf(d.w * rstd * g4.w + b4.w);
    *(ushort4*)(y + (size_t)row * MD + tid * 4) = o;
}

// ---------------------------------------------------------------------------
// fp32 -> bf16 cast (enc_out). n = grid*256*4 elements exactly.
// ---------------------------------------------------------------------------
__global__ __launch_bounds__(256) void cast_bf16(
    const float* __restrict__ x, unsigned short* __restrict__ y)
{
    int i = blockIdx.x * 256 + threadIdx.x;
    float4 v = ((const float4*)x)[i];
    ushort4 o;
    o.x = f2bf(v.x); o.y = f2bf(v.y); o.z = f2bf(v.z); o.w = f2bf(v.w);
    ((ushort4*)y)[i] = o;
}

// ---------------------------------------------------------------------------
// Batched transpose + cast: X fp32 (batch,R,C) -> Y bf16 (batch,C,R).
// ---------------------------------------------------------------------------
__global__ __launch_bounds__(256) void transpose_cast(
    const float* __restrict__ X, unsigned short* __restrict__ Y, int R, int C)
{
    __shared__ float tile[32][33];
    int bz = blockIdx.z;
    int r0 = blockIdx.y * 32, c0 = blockIdx.x * 32;
    const float* Xb = X + (size_t)bz * R * C;
    unsigned short* Yb = Y + (size_t)bz * R * C;
    int tx = threadIdx.x & 31, ty = threadIdx.x >> 5;
    #pragma unroll
    for (int i = 0; i < 4; i++)
        tile[ty + i*8][tx] = Xb[(size_t)(r0 + ty + i*8) * C + c0 + tx];
    __syncthreads();
    #pragma unroll
    for (int i = 0; i < 4; i++)
        Yb[(size_t)(c0 + ty + i*8) * R + r0 + tx] = f2bf(tile[tx][ty + i*8]);
}

// ---------------------------------------------------------------------------
// Shared bf16 MFMA GEMM body, DOUBLE-BUFFERED single-barrier K-loop.
// Tile 128x128, BK=64, 4 waves x (4x4) 16x16x32, fp32 accum.
// flags: 1 = write V^T layout (b,h,d,t) bf16
//        2 = fp32 atomicAdd into Cout (residual / split-K accumulate)
//        4 = add bias[col]
//        8 = ReLU
// ---------------------------------------------------------------------------
#define BKK 64
#define ASZ (128 * BKK)

__device__ __forceinline__ void stage_tiles(
    unsigned short* As, unsigned short* Bs,
    const unsigned short* __restrict__ A, int lda,
    const unsigned short* __restrict__ BT, int ldb,
    int row0, int col0, int kt)
{
    int tid = threadIdx.x;
    #pragma unroll
    for (int it = 0; it < 4; it++) {
        int idx = it * 256 + tid;
        int r = idx >> 3, c = (idx & 7) * 8;
        load16_lds(A + (size_t)(row0 + r) * lda + kt + c, &As[idx * 8]);
    }
    #pragma unroll
    for (int it = 0; it < 4; it++) {
        int idx = it * 256 + tid;
        int r = idx >> 3, c = (idx & 7) * 8;
        load16_lds(BT + (size_t)(col0 + r) * ldb + kt + c, &Bs[idx * 8]);
    }
}

__device__ __forceinline__ void gemm_body(
    unsigned short* As, unsigned short* Bs,
    const unsigned short* __restrict__ A, int lda,
    const unsigned short* __restrict__ BT, int ldb,
    void* __restrict__ Cout, int ldc, int Kdim, int flags,
    const float* __restrict__ bias, int row0, int col0)
{
    int tid = threadIdx.x;
    int lane = tid & 63;
    int wave = tid >> 6;
    int mr = (wave & 1) * 64;
    int nc = (wave >> 1) * 64;
    int lr = lane & 15;
    int quad = lane >> 4;

    f32x4 acc[4][4];
    #pragma unroll
    for (int i = 0; i < 4; i++)
        #pragma unroll
        for (int j = 0; j < 4; j++) acc[i][j] = (f32x4)0.0f;

    const int NKi = Kdim >> 6;
    // prologue: stage k=0 into buffer 0, wait
    stage_tiles(As, Bs, A, lda, BT, ldb, row0, col0, 0);
    __syncthreads();

    for (int k = 0; k < NKi; k++) {
        unsigned short* cA = As + (k & 1) * ASZ;
        unsigned short* cB = Bs + (k & 1) * ASZ;
        // issue next-tile DMA first; it overlaps this iteration's compute.
        if (k + 1 < NKi)
            stage_tiles(As + ((k + 1) & 1) * ASZ, Bs + ((k + 1) & 1) * ASZ,
                        A, lda, BT, ldb, row0, col0, (k + 1) * BKK);
        #pragma unroll
        for (int ks = 0; ks < 2; ks++) {
            bf16x8 af[4], bfr[4];
            #pragma unroll
            for (int i = 0; i < 4; i++)
                af[i] = *(const bf16x8*)&cA[(mr + i*16 + lr) * BKK + ks*32 + quad*8];
            #pragma unroll
            for (int j = 0; j < 4; j++)
                bfr[j] = *(const bf16x8*)&cB[(nc + j*16 + lr) * BKK + ks*32 + quad*8];
            #pragma unroll
            for (int i = 0; i < 4; i++)
                #pragma unroll
                for (int j = 0; j < 4; j++)
                    acc[i][j] = __builtin_amdgcn_mfma_f32_16x16x32_bf16(
                        af[i], bfr[j], acc[i][j], 0, 0, 0);
        }
        // one barrier per iter: waits compute ds_reads (lgkm) AND the k+1
        // stage DMA (vmcnt) -- which has had the whole compute phase in flight.
        __syncthreads();
    }

    float bvj[4];
    if (flags & 4) {
        #pragma unroll
        for (int j = 0; j < 4; j++) bvj[j] = bias[col0 + nc + j*16 + lr];
    } else {
        #pragma unroll
        for (int j = 0; j < 4; j++) bvj[j] = 0.0f;
    }

    if (flags & 1) {
        // V^T store: vbt[((b*8+h)*128 + d) * NT + t], 4 consecutive t packed
        unsigned short* V = (unsigned short*)Cout;
        #pragma unroll
        for (int i = 0; i < 4; i++) {
            int grow0 = row0 + mr + i*16 + quad*4;
            int bb = grow0 >> 10, tt = grow0 & 1023;
            #pragma unroll
            for (int j = 0; j < 4; j++) {
                int gcol = col0 + nc + j*16 + lr;
                int hh = gcol >> 7, dd = gcol & 127;
                ushort4 pk;
                pk.x = f2bf(acc[i][j][0]); pk.y = f2bf(acc[i][j][1]);
                pk.z = f2bf(acc[i][j][2]); pk.w = f2bf(acc[i][j][3]);
                *(ushort4*)(V + (((size_t)(bb*NH + hh)*HD + dd) * NT + tt)) = pk;
            }
        }
    } else if (flags & 2) {
        float* Cf = (float*)Cout;
        #pragma unroll
        for (int i = 0; i < 4; i++) {
            int grow0 = row0 + mr + i*16 + quad*4;
            #pragma unroll
            for (int j = 0; j < 4; j++) {
                int gcol = col0 + nc + j*16 + lr;
                #pragma unroll
                for (int r = 0; r < 4; r++) {
                    float v = acc[i][j][r] + bvj[j];
                    atomicAdd(&Cf[(size_t)(grow0 + r) * ldc + gcol], v);
                }
            }
        }
    } else {
        unsigned short* Cb = (unsigned short*)Cout;
        #pragma unroll
        for (int i = 0; i < 4; i++) {
            int grow0 = row0 + mr + i*16 + quad*4;
            #pragma unroll
            for (int j = 0; j < 4; j++) {
                int gcol = col0 + nc + j*16 + lr;
                #pragma unroll
                for (int r = 0; r < 4; r++) {
                    float v = acc[i][j][r] + bvj[j];
                    if (flags & 8) v = fmaxf(v, 0.0f);
                    Cb[(size_t)(grow0 + r) * ldc + gcol] = f2bf(v);
                }
            }
        }
    }
}

// Generic GEMM with K-split over blockIdx.z (Kper = K per split).
__global__ __launch_bounds__(256) void gemm_bf16(
    const unsigned short* __restrict__ A, int lda,
    const unsigned short* __restrict__ BT, int ldb,
    void* __restrict__ Cout, int ldc, int Kper, int flags,
    const float* __restrict__ bias)
{
    __shared__ unsigned short As[2 * ASZ];
    __shared__ unsigned short Bs[2 * ASZ];
    int row0 = blockIdx.y * 128, col0 = blockIdx.x * 128;
    int kbase = blockIdx.z * Kper;
    if (blockIdx.z) flags &= ~4;      // bias only once
    gemm_body(As, Bs, A + kbase, lda, BT + kbase, ldb, Cout, ldc,
              Kper, flags, bias, row0, col0);
}

// Fused Q/K/V projection: blockIdx.x in [0,24): weight = x>>3, col = (x&7)*128.
// Q uses Aq, K/V use Akv. V output goes to V^T layout.
__global__ __launch_bounds__(256) void gemm_qkv(
    const unsigned short* __restrict__ Aq,
    const unsigned short* __restrict__ Akv,
    const unsigned short* __restrict__ BTq,
    const unsigned short* __restrict__ BTk,
    const unsigned short* __restrict__ BTv,
    unsigned short* __restrict__ qb,
    unsigned short* __restrict__ kb,
    unsigned short* __restrict__ vbt)
{
    __shared__ unsigned short As[2 * ASZ];
    __shared__ unsigned short Bs[2 * ASZ];
    int w = blockIdx.x >> 3;
    int col0 = (blockIdx.x & 7) * 128;
    int row0 = blockIdx.y * 128;
    const unsigned short* A  = (w == 0) ? Aq : Akv;
    const unsigned short* BT = (w == 0) ? BTq : (w == 1) ? BTk : BTv;
    void* C  = (w == 0) ? (void*)qb : (w == 1) ? (void*)kb : (void*)vbt;
    int flags = (w == 2) ? 1 : 0;
    gemm_body(As, Bs, A, MD, BT, MD, C, MD, MD, flags, nullptr, row0, col0);
}

// ---------------------------------------------------------------------------
// MFMA flash attention v3: LDS diet for occupancy.
//   - Q fragments loaded per-lane straight from global (no Qs tile: Q has no
//     cross-wave reuse; K/V keep LDS for their 4-way reuse).
//   - Ks/Vs/Ps stored unpadded with XOR swizzle (short_off ^= (row&7)<<3):
//     power-of-2 strides without bank conflicts (2-way aliasing only = free).
//     LDS = 16K (Ks 64x128) + 16K (Vs 128x64) + 8K (Ps 4x16x64) = 40 KB
//     -> 3-4 blocks/CU (was 2), doubling the wave pool that hides the
//     serial softmax latency chain.
//   - defer-max (T13, THR=8): skip alpha-rescale when the tile max doesn't
//     beat the running max by >8; wave-uniform branch.
//   - reg-staged K/V double-buffer (T14) + causal balance remap retained.
// ---------------------------------------------------------------------------
#define KVB 64

__global__ __launch_bounds__(256) void attn_mfma(
    const unsigned short* __restrict__ qb, const unsigned short* __restrict__ kb,
    const unsigned short* __restrict__ vbt, unsigned short* __restrict__ pr,
    int causal)
{
    __shared__ unsigned short Ks[64 * 128];    // [key][d], swizzled
    __shared__ unsigned short Vs[128 * 64];    // [d][key], swizzled
    __shared__ unsigned short Ps[4 * 16 * 64]; // per-wave [qrow][key], swizzled

    int tid = threadIdx.x;
    int lane = tid & 63, wave = tid >> 6;
    int lr = lane & 15, quad = lane >> 4;

    int qt, bh;
    if (causal) {
        int bid = blockIdx.x + 16 * blockIdx.y;   // dispatch order, x fastest
        int half = bid >> 8, j = bid & 255;
        qt = half ? (15 - (j & 15)) : (j & 15);
        bh = (half << 4) | (j >> 4);
    } else {
        qt = blockIdx.x; bh = blockIdx.y;
    }
    int b = bh >> 3, h = bh & 7;
    int q0 = qt * 64;
    const float scale = 0.08838834764831845f;  // 1/sqrt(128)

    const unsigned short* kbase = kb + (size_t)(b * NT) * MD + h * HD;
    const unsigned short* vbase = vbt + (size_t)((b * NH + h) * HD) * NT;

    // ---- issue chunk-0 K/V global loads ----
    uint4 kreg[4], vreg[4];
    #pragma unroll
    for (int it = 0; it < 4; it++) {
        int idx = it * 256 + tid;
        int r = idx >> 4, c = (idx & 15) * 8;
        kreg[it] = *(const uint4*)(kbase + (size_t)r * MD + c);
    }
    #pragma unroll
    for (int it = 0; it < 4; it++) {
        int idx = it * 256 + tid;
        int r = idx >> 3, c = (idx & 7) * 8;
        vreg[it] = *(const uint4*)(vbase + (size_t)r * NT + c);
    }

    // ---- Q fragments: per-lane direct global load (one-time, L2-hot) ----
    const unsigned short* qrow_p =
        qb + (size_t)(b*NQ + q0 + wave*16 + lr) * MD + h*HD;
    bf16x8 aq[4];
    #pragma unroll
    for (int dk = 0; dk < 4; dk++)
        aq[dk] = *(const bf16x8*)(qrow_p + dk*32 + quad*8);

    f32x4 acc[8];
    #pragma unroll
    for (int n = 0; n < 8; n++) acc[n] = (f32x4)0.0f;
    float m_run[4], l_run[4];
    #pragma unroll
    for (int r = 0; r < 4; r++) { m_run[r] = -1e30f; l_run[r] = 0.0f; }

    unsigned short* Pw = &Ps[wave * 16 * 64];
    int nch = causal ? (qt + 1) : (NT / KVB);
    int grow_base = q0 + wave*16 + quad*4;
    int swz = (lr & 7) << 3;   // XOR for rows where (row&7)==(lr&7)

    for (int tc = 0; tc < nch; tc++) {
        __syncthreads();            // previous compute done reading Ks/Vs
        // staged regs -> LDS (swizzled; vmcnt waits here, loads have had the
        // whole previous compute phase in flight)
        #pragma unroll
        for (int it = 0; it < 4; it++) {
            int idx = it * 256 + tid;
            int r = idx >> 4, c16 = idx & 15;
            *(uint4*)&Ks[r * 128 + ((c16 * 8) ^ ((r & 7) << 3))] = kreg[it];
        }
        #pragma unroll
        for (int it = 0; it < 4; it++) {
            int idx = it * 256 + tid;
            int r = idx >> 3, c8 = idx & 7;
            *(uint4*)&Vs[r * 64 + ((c8 * 8) ^ ((r & 7) << 3))] = vreg[it];
        }
        // issue next-chunk loads; they overlap the compute below
        if (tc + 1 < nch) {
            int t0n = (tc + 1) * KVB;
            #pragma unroll
            for (int it = 0; it < 4; it++) {
                int idx = it * 256 + tid;
                int r = idx >> 4, c = (idx & 15) * 8;
                kreg[it] = *(const uint4*)(kbase + (size_t)(t0n + r) * MD + c);
            }
            #pragma unroll
            for (int it = 0; it < 4; it++) {
                int idx = it * 256 + tid;
                int r = idx >> 3, c = (idx & 7) * 8;
                vreg[it] = *(const uint4*)(vbase + (size_t)r * NT + t0n + c);
            }
        }
        __syncthreads();            // Ks/Vs visible to all waves

        int t0 = tc * KVB;

        // ---- QK^T: 4 k-slices of 16 keys, K-dim 128 over 4 dk ----
        f32x4 s[4];
        #pragma unroll
        for (int kt = 0; kt < 4; kt++) s[kt] = (f32x4)0.0f;
        __builtin_amdgcn_s_setprio(1);
        #pragma unroll
        for (int dk = 0; dk < 4; dk++) {
            #pragma unroll
            for (int kt = 0; kt < 4; kt++) {
                bf16x8 bk = *(const bf16x8*)
                    &Ks[(kt*16 + lr) * 128 + ((dk*32 + quad*8) ^ swz)];
                s[kt] = __builtin_amdgcn_mfma_f32_16x16x32_bf16(aq[dk], bk, s[kt], 0, 0, 0);
            }
        }
        __builtin_amdgcn_s_setprio(0);

        // ---- online softmax over 64 keys, defer-max (T13) ----
        float mxt[4];
        #pragma unroll
        for (int r = 0; r < 4; r++) {
            #pragma unroll
            for (int kt = 0; kt < 4; kt++) {
                float x = s[kt][r] * scale;
                if (causal && (t0 + kt*16 + lr > grow_base + r)) x = -1e30f;
                s[kt][r] = x;
            }
            float mx = fmaxf(fmaxf(s[0][r], s[1][r]), fmaxf(s[2][r], s[3][r]));
            #pragma unroll
            for (int off = 1; off < 16; off <<= 1)
                mx = fmaxf(mx, __shfl_xor(mx, off));
            mxt[r] = mx;
        }
        float need = fmaxf(fmaxf(mxt[0]-m_run[0], mxt[1]-m_run[1]),
                           fmaxf(mxt[2]-m_run[2], mxt[3]-m_run[3]));
        if (!__all(need <= 8.0f)) {
            #pragma unroll
            for (int r = 0; r < 4; r++) {
                float mx = fmaxf(mxt[r], m_run[r]);
                float alpha = __expf(m_run[r] - mx);
                m_run[r] = mx;
                l_run[r] *= alpha;
                #pragma unroll
                for (int n = 0; n < 8; n++) acc[n][r] *= alpha;
            }
        }
        #pragma unroll
        for (int r = 0; r < 4; r++) {
            int prow = quad*4 + r;
            int pswz = (prow & 7) << 3;
            float psum = 0.0f;
            #pragma unroll
            for (int kt = 0; kt < 4; kt++) {
                float p = __expf(s[kt][r] - m_run[r]);
                Pw[prow * 64 + ((kt*16 + lr) ^ pswz)] = f2bf(p);
                psum += p;
            }
            #pragma unroll
            for (int off = 1; off < 16; off <<= 1)
                psum += __shfl_xor(psum, off);
            l_run[r] += psum;
        }

        // ---- PV: P (16x64) x V^T fragments ----
        bf16x8 ap0 = *(const bf16x8*)&Pw[lr * 64 + ((quad * 8) ^ swz)];
        bf16x8 ap1 = *(const bf16x8*)&Pw[lr * 64 + ((32 + quad * 8) ^ swz)];
        __builtin_amdgcn_s_setprio(1);
        #pragma unroll
        for (int n = 0; n < 8; n++) {
            bf16x8 bv0 = *(const bf16x8*)
                &Vs[(n*16 + lr) * 64 + ((quad * 8) ^ swz)];
            bf16x8 bv1 = *(const bf16x8*)
                &Vs[(n*16 + lr) * 64 + ((32 + quad * 8) ^ swz)];
            acc[n] = __builtin_amdgcn_mfma_f32_16x16x32_bf16(ap0, bv0, acc[n], 0, 0, 0);
            acc[n] = __builtin_amdgcn_mfma_f32_16x16x32_bf16(ap1, bv1, acc[n], 0, 0, 0);
        }
        __builtin_amdgcn_s_setprio(0);
    }

    float linv[4];
    #pragma unroll
    for (int r = 0; r < 4; r++) linv[r] = 1.0f / l_run[r];
    #pragma unroll
    for (int n = 0; n < 8; n++) {
        int gcol = h*HD + n*16 + lr;
        #pragma unroll
        for (int r = 0; r < 4; r++) {
            int grow = q0 + wave*16 + quad*4 + r;
            pr[(size_t)(b*NQ + grow) * MD + gcol] = f2bf(acc[n][r] * linv[r]);
        }
    }
}

// ---------------------------------------------------------------------------
extern "C" void kernel_launch(void* const* d_in, const int* in_sizes, int n_in,
                              void* d_out, int out_size, void* d_ws, size_t ws_size,
                              hipStream_t stream)
{
    const float* enc  = (const float*)d_in[0];
    const float* x    = (const float*)d_in[1];
    const float* swq  = (const float*)d_in[5];
    const float* swk  = (const float*)d_in[6];
    const float* swv  = (const float*)d_in[7];
    const float* swo  = (const float*)d_in[8];
    const float* cwq  = (const float*)d_in[9];
    const float* cwk  = (const float*)d_in[10];
    const float* cwv  = (const float*)d_in[11];
    const float* cwo  = (const float*)d_in[12];
    const float* w1   = (const float*)d_in[13];
    const float* b1   = (const float*)d_in[14];
    const float* w2   = (const float*)d_in[15];
    const float* b2   = (const float*)d_in[16];
    const float* ln1g = (const float*)d_in[17];
    const float* ln1b = (const float*)d_in[18];
    const float* ln2g = (const float*)d_in[19];
    const float* ln2b = (const float*)d_in[20];
    const float* ln3g = (const float*)d_in[21];
    const float* ln3b = (const float*)d_in[22];

    float* h = (float*)d_out;
    unsigned short* u = (unsigned short*)d_ws;
    const size_t MW = 1024 * 1024;
    unsigned short* nb   = u;             // 4M ushort
    unsigned short* encb = u + 4*MW;      // 4M
    unsigned short* qb   = u + 8*MW;      // 4M
    unsigned short* kb   = u + 12*MW;     // 4M
    unsigned short* vbt  = u + 16*MW;     // 4M
    unsigned short* pr   = u + 20*MW;     // 4M
    unsigned short* sb   = qb;            // aliases qb..pr (16M), FFN-only
    unsigned short* wb   = u + 24*MW;

    bool upfront = ws_size >= (size_t)240 * MW;

    hipMemcpyAsync(h, x, 4*MW*sizeof(float), hipMemcpyDeviceToDevice, stream);

    dim3 tb(256);
    cast_bf16<<<4096, tb, 0, stream>>>(enc, encb);

    if (upfront) {
        transpose_cast<<<dim3(4,32,48),  tb, 0, stream>>>(swq, wb + 0*MW,  1024, 128);
        transpose_cast<<<dim3(4,32,48),  tb, 0, stream>>>(swk, wb + 6*MW,  1024, 128);
        transpose_cast<<<dim3(4,32,48),  tb, 0, stream>>>(swv, wb + 12*MW, 1024, 128);
        transpose_cast<<<dim3(32,32,6),  tb, 0, stream>>>(swo, wb + 18*MW, 1024, 1024);
        transpose_cast<<<dim3(4,32,48),  tb, 0, stream>>>(cwq, wb + 24*MW, 1024, 128);
        transpose_cast<<<dim3(4,32,48),  tb, 0, stream>>>(cwk, wb + 30*MW, 1024, 128);
        transpose_cast<<<dim3(4,32,48),  tb, 0, stream>>>(cwv, wb + 36*MW, 1024, 128);
        transpose_cast<<<dim3(32,32,6),  tb, 0, stream>>>(cwo, wb + 42*MW, 1024, 1024);
        transpose_cast<<<dim3(128,32,6), tb, 0, stream>>>(w1,  wb + 48*MW, 1024, 4096);
        transpose_cast<<<dim3(32,128,6), tb, 0, stream>>>(w2,  wb + 72*MW, 4096, 1024);
    }

    dim3 gQKV(24, 32), gO(8, 32, 2), gF1(32, 32), gF2(8, 32, 2), gA(16, 32);

    for (int l = 0; l < NL; l++) {
        unsigned short *pwq, *pwk, *pwv, *pwo, *pcq, *pck, *pcv, *pco, *pw1, *pw2;
        if (upfront) {
            pwq = wb + 0*MW  + l*MW;  pwk = wb + 6*MW  + l*MW;
            pwv = wb + 12*MW + l*MW;  pwo = wb + 18*MW + l*MW;
            pcq = wb + 24*MW + l*MW;  pck = wb + 30*MW + l*MW;
            pcv = wb + 36*MW + l*MW;  pco = wb + 42*MW + l*MW;
            pw1 = wb + 48*MW + l*4*MW; pw2 = wb + 72*MW + l*4*MW;
        } else {
            pwq = wb;        pwk = wb + 1*MW; pwv = wb + 2*MW; pwo = wb + 3*MW;
            pcq = wb + 4*MW; pck = wb + 5*MW; pcv = wb + 6*MW; pco = wb + 7*MW;
            pw1 = wb + 8*MW; pw2 = wb + 12*MW;
            transpose_cast<<<dim3(4,32,8),   tb, 0, stream>>>(swq + l*MW,   pwq, 1024, 128);
            transpose_cast<<<dim3(4,32,8),   tb, 0, stream>>>(swk + l*MW,   pwk, 1024, 128);
            transpose_cast<<<dim3(4,32,8),   tb, 0, stream>>>(swv + l*MW,   pwv, 1024, 128);
            transpose_cast<<<dim3(32,32,1),  tb, 0, stream>>>(swo + l*MW,   pwo, 1024, 1024);
            transpose_cast<<<dim3(4,32,8),   tb, 0, stream>>>(cwq + l*MW,   pcq, 1024, 128);
            transpose_cast<<<dim3(4,32,8),   tb, 0, stream>>>(cwk + l*MW,   pck, 1024, 128);
            transpose_cast<<<dim3(4,32,8),   tb, 0, stream>>>(cwv + l*MW,   pcv, 1024, 128);
            transpose_cast<<<dim3(32,32,1),  tb, 0, stream>>>(cwo + l*MW,   pco, 1024, 1024);
            transpose_cast<<<dim3(128,32,1), tb, 0, stream>>>(w1 + l*4*MW,  pw1, 1024, 4096);
            transpose_cast<<<dim3(32,128,1), tb, 0, stream>>>(w2 + l*4*MW,  pw2, 4096, 1024);
        }

        // ---- self attention ----
        ln_kernel<<<ROWS, tb, 0, stream>>>(h, nb, ln1g + l*MD, ln1b + l*MD);
        gemm_qkv<<<gQKV, tb, 0, stream>>>(nb, nb, pwq, pwk, pwv, qb, kb, vbt);
        attn_mfma<<<gA, tb, 0, stream>>>(qb, kb, vbt, pr, 1);
        gemm_bf16<<<gO, tb, 0, stream>>>(pr, MD, pwo, MD, h, MD, 512, 2, nullptr);

        // ---- cross attention ----
        ln_kernel<<<ROWS, tb, 0, stream>>>(h, nb, ln2g + l*MD, ln2b + l*MD);
        gemm_qkv<<<gQKV, tb, 0, stream>>>(nb, encb, pcq, pck, pcv, qb, kb, vbt);
        attn_mfma<<<gA, tb, 0, stream>>>(qb, kb, vbt, pr, 0);
        gemm_bf16<<<gO, tb, 0, stream>>>(pr, MD, pco, MD, h, MD, 512, 2, nullptr);

        // ---- FFN ----
        ln_kernel<<<ROWS, tb, 0, stream>>>(h, nb, ln3g + l*MD, ln3b + l*MD);
        gemm_bf16<<<gF1, tb, 0, stream>>>(nb, MD, pw1, MD, sb, FF, 1024, 4 | 8, b1 + l*FF);
        gemm_bf16<<<gF2, tb, 0, stream>>>(sb, FF, pw2, FF, h, MD, 2048, 2 | 4, b2 + l*MD);
    }
}

// Round 4
// 2991.106 us; speedup vs baseline: 1.2261x; 1.2261x over previous
//
#include <hip/hip_runtime.h>
#include <math.h>

// Problem constants (Decoder_88871463288984)
#define NL 6
#define NH 8
#define MD 1024
#define HD 128
#define FF 4096
#define NB 4
#define NQ 1024
#define NT 1024
#define ROWS (NB*NQ)   // 4096

typedef __attribute__((ext_vector_type(8))) short bf16x8;
typedef __attribute__((ext_vector_type(4))) float f32x4;

// fp32 -> bf16, round-to-nearest-even
__device__ __forceinline__ unsigned short f2bf(float f) {
    unsigned int u = __float_as_uint(f);
    u += 0x7fffu + ((u >> 16) & 1u);
    return (unsigned short)(u >> 16);
}

// async global->LDS, 16 bytes per lane (dst must be wave-uniform base + lane*16)
__device__ __forceinline__ void load16_lds(const unsigned short* g, unsigned short* l) {
    __builtin_amdgcn_global_load_lds(
        (const __attribute__((address_space(1))) unsigned int*)g,
        (__attribute__((address_space(3))) unsigned int*)l, 16, 0, 0);
}

// ---------------------------------------------------------------------------
// LayerNorm: fp32 in (h), bf16 out. One block per row of 1024.
// ---------------------------------------------------------------------------
__global__ __launch_bounds__(256) void ln_kernel(
    const float* __restrict__ x, unsigned short* __restrict__ y,
    const float* __restrict__ g, const float* __restrict__ b)
{
    __shared__ float sdata[8];
    int row = blockIdx.x;
    int tid = threadIdx.x;
    const float* xr = x + (size_t)row * MD;
    float4 v = ((const float4*)xr)[tid];
    float s = v.x + v.y + v.z + v.w;
    #pragma unroll
    for (int o = 32; o > 0; o >>= 1) s += __shfl_down(s, o, 64);
    if ((tid & 63) == 0) sdata[tid >> 6] = s;
    __syncthreads();
    if (tid == 0) sdata[4] = sdata[0] + sdata[1] + sdata[2] + sdata[3];
    __syncthreads();
    float mean = sdata[4] * (1.0f / MD);
    float4 d = make_float4(v.x - mean, v.y - mean, v.z - mean, v.w - mean);
    float sq = d.x*d.x + d.y*d.y + d.z*d.z + d.w*d.w;
    #pragma unroll
    for (int o = 32; o > 0; o >>= 1) sq += __shfl_down(sq, o, 64);
    __syncthreads();
    if ((tid & 63) == 0) sdata[tid >> 6] = sq;
    __syncthreads();
    if (tid == 0) sdata[4] = sdata[0] + sdata[1] + sdata[2] + sdata[3];
    __syncthreads();
    float var = sdata[4] * (1.0f / MD);
    float rstd = rsqrtf(var + 1e-5f);
    float4 g4 = ((const float4*)g)[tid];
    float4 b4 = ((const float4*)b)[tid];
    ushort4 o;
    o.x = f2bf(d.x * rstd * g4.x + b4.x);
    o.y = f2bf(d.y * rstd * g4.y + b4.y);
    o.z = f2bf(d.z * rstd * g4.z + b4.z);
    o.w = f2bf(d.w * rstd * g4.w + b4.w);
    *(ushort4*)(y + (size_t)row * MD + tid * 4) = o;
}

// ---------------------------------------------------------------------------
// fp32 -> bf16 cast (enc_out). n = grid*256*4 elements exactly.
// ---------------------------------------------------------------------------
__global__ __launch_bounds__(256) void cast_bf16(
    const float* __restrict__ x, unsigned short* __restrict__ y)
{
    int i = blockIdx.x * 256 + threadIdx.x;
    float4 v = ((const float4*)x)[i];
    ushort4 o;
    o.x = f2bf(v.x); o.y = f2bf(v.y); o.z = f2bf(v.z); o.w = f2bf(v.w);
    ((ushort4*)y)[i] = o;
}

// ---------------------------------------------------------------------------
// Batched transpose + cast: X fp32 (batch,R,C) -> Y bf16 (batch,C,R).
// ---------------------------------------------------------------------------
__global__ __launch_bounds__(256) void transpose_cast(
    const float* __restrict__ X, unsigned short* __restrict__ Y, int R, int C)
{
    __shared__ float tile[32][33];
    int bz = blockIdx.z;
    int r0 = blockIdx.y * 32, c0 = blockIdx.x * 32;
    const float* Xb = X + (size_t)bz * R * C;
    unsigned short* Yb = Y + (size_t)bz * R * C;
    int tx = threadIdx.x & 31, ty = threadIdx.x >> 5;
    #pragma unroll
    for (int i = 0; i < 4; i++)
        tile[ty + i*8][tx] = Xb[(size_t)(r0 + ty + i*8) * C + c0 + tx];
    __syncthreads();
    #pragma unroll
    for (int i = 0; i < 4; i++)
        Yb[(size_t)(c0 + ty + i*8) * R + r0 + tx] = f2bf(tile[tx][ty + i*8]);
}

// ---------------------------------------------------------------------------
// Shared bf16 MFMA GEMM body, DOUBLE-BUFFERED single-barrier K-loop.
// Tile 128x128, BK=64, 4 waves x (4x4) 16x16x32, fp32 accum.
// flags: 1 = write V^T layout (b,h,d,t) bf16
//        2 = fp32 atomicAdd into Cout (residual / split-K accumulate)
//        4 = add bias[col]
//        8 = ReLU
// ---------------------------------------------------------------------------
#define BKK 64
#define ASZ (128 * BKK)

__device__ __forceinline__ void stage_tiles(
    unsigned short* As, unsigned short* Bs,
    const unsigned short* __restrict__ A, int lda,
    const unsigned short* __restrict__ BT, int ldb,
    int row0, int col0, int kt)
{
    int tid = threadIdx.x;
    #pragma unroll
    for (int it = 0; it < 4; it++) {
        int idx = it * 256 + tid;
        int r = idx >> 3, c = (idx & 7) * 8;
        load16_lds(A + (size_t)(row0 + r) * lda + kt + c, &As[idx * 8]);
    }
    #pragma unroll
    for (int it = 0; it < 4; it++) {
        int idx = it * 256 + tid;
        int r = idx >> 3, c = (idx & 7) * 8;
        load16_lds(BT + (size_t)(col0 + r) * ldb + kt + c, &Bs[idx * 8]);
    }
}

__device__ __forceinline__ void gemm_body(
    unsigned short* As, unsigned short* Bs,
    const unsigned short* __restrict__ A, int lda,
    const unsigned short* __restrict__ BT, int ldb,
    void* __restrict__ Cout, int ldc, int Kdim, int flags,
    const float* __restrict__ bias, int row0, int col0)
{
    int tid = threadIdx.x;
    int lane = tid & 63;
    int wave = tid >> 6;
    int mr = (wave & 1) * 64;
    int nc = (wave >> 1) * 64;
    int lr = lane & 15;
    int quad = lane >> 4;

    f32x4 acc[4][4];
    #pragma unroll
    for (int i = 0; i < 4; i++)
        #pragma unroll
        for (int j = 0; j < 4; j++) acc[i][j] = (f32x4)0.0f;

    const int NKi = Kdim >> 6;
    // prologue: stage k=0 into buffer 0, wait
    stage_tiles(As, Bs, A, lda, BT, ldb, row0, col0, 0);
    __syncthreads();

    for (int k = 0; k < NKi; k++) {
        unsigned short* cA = As + (k & 1) * ASZ;
        unsigned short* cB = Bs + (k & 1) * ASZ;
        // issue next-tile DMA first; it overlaps this iteration's compute.
        if (k + 1 < NKi)
            stage_tiles(As + ((k + 1) & 1) * ASZ, Bs + ((k + 1) & 1) * ASZ,
                        A, lda, BT, ldb, row0, col0, (k + 1) * BKK);
        #pragma unroll
        for (int ks = 0; ks < 2; ks++) {
            bf16x8 af[4], bfr[4];
            #pragma unroll
            for (int i = 0; i < 4; i++)
                af[i] = *(const bf16x8*)&cA[(mr + i*16 + lr) * BKK + ks*32 + quad*8];
            #pragma unroll
            for (int j = 0; j < 4; j++)
                bfr[j] = *(const bf16x8*)&cB[(nc + j*16 + lr) * BKK + ks*32 + quad*8];
            #pragma unroll
            for (int i = 0; i < 4; i++)
                #pragma unroll
                for (int j = 0; j < 4; j++)
                    acc[i][j] = __builtin_amdgcn_mfma_f32_16x16x32_bf16(
                        af[i], bfr[j], acc[i][j], 0, 0, 0);
        }
        // one barrier per iter: waits compute ds_reads (lgkm) AND the k+1
        // stage DMA (vmcnt) -- which has had the whole compute phase in flight.
        __syncthreads();
    }

    float bvj[4];
    if (flags & 4) {
        #pragma unroll
        for (int j = 0; j < 4; j++) bvj[j] = bias[col0 + nc + j*16 + lr];
    } else {
        #pragma unroll
        for (int j = 0; j < 4; j++) bvj[j] = 0.0f;
    }

    if (flags & 1) {
        // V^T store: vbt[((b*8+h)*128 + d) * NT + t], 4 consecutive t packed
        unsigned short* V = (unsigned short*)Cout;
        #pragma unroll
        for (int i = 0; i < 4; i++) {
            int grow0 = row0 + mr + i*16 + quad*4;
            int bb = grow0 >> 10, tt = grow0 & 1023;
            #pragma unroll
            for (int j = 0; j < 4; j++) {
                int gcol = col0 + nc + j*16 + lr;
                int hh = gcol >> 7, dd = gcol & 127;
                ushort4 pk;
                pk.x = f2bf(acc[i][j][0]); pk.y = f2bf(acc[i][j][1]);
                pk.z = f2bf(acc[i][j][2]); pk.w = f2bf(acc[i][j][3]);
                *(ushort4*)(V + (((size_t)(bb*NH + hh)*HD + dd) * NT + tt)) = pk;
            }
        }
    } else if (flags & 2) {
        float* Cf = (float*)Cout;
        #pragma unroll
        for (int i = 0; i < 4; i++) {
            int grow0 = row0 + mr + i*16 + quad*4;
            #pragma unroll
            for (int j = 0; j < 4; j++) {
                int gcol = col0 + nc + j*16 + lr;
                #pragma unroll
                for (int r = 0; r < 4; r++) {
                    float v = acc[i][j][r] + bvj[j];
                    atomicAdd(&Cf[(size_t)(grow0 + r) * ldc + gcol], v);
                }
            }
        }
    } else {
        unsigned short* Cb = (unsigned short*)Cout;
        #pragma unroll
        for (int i = 0; i < 4; i++) {
            int grow0 = row0 + mr + i*16 + quad*4;
            #pragma unroll
            for (int j = 0; j < 4; j++) {
                int gcol = col0 + nc + j*16 + lr;
                #pragma unroll
                for (int r = 0; r < 4; r++) {
                    float v = acc[i][j][r] + bvj[j];
                    if (flags & 8) v = fmaxf(v, 0.0f);
                    Cb[(size_t)(grow0 + r) * ldc + gcol] = f2bf(v);
                }
            }
        }
    }
}

// Generic GEMM with K-split over blockIdx.z (Kper = K per split).
__global__ __launch_bounds__(256) void gemm_bf16(
    const unsigned short* __restrict__ A, int lda,
    const unsigned short* __restrict__ BT, int ldb,
    void* __restrict__ Cout, int ldc, int Kper, int flags,
    const float* __restrict__ bias)
{
    __shared__ unsigned short As[2 * ASZ];
    __shared__ unsigned short Bs[2 * ASZ];
    int row0 = blockIdx.y * 128, col0 = blockIdx.x * 128;
    int kbase = blockIdx.z * Kper;
    if (blockIdx.z) flags &= ~4;      // bias only once
    gemm_body(As, Bs, A + kbase, lda, BT + kbase, ldb, Cout, ldc,
              Kper, flags, bias, row0, col0);
}

// Fused Q/K/V projection: blockIdx.x in [0,24): weight = x>>3, col = (x&7)*128.
// Q uses Aq, K/V use Akv. V output goes to V^T layout.
__global__ __launch_bounds__(256) void gemm_qkv(
    const unsigned short* __restrict__ Aq,
    const unsigned short* __restrict__ Akv,
    const unsigned short* __restrict__ BTq,
    const unsigned short* __restrict__ BTk,
    const unsigned short* __restrict__ BTv,
    unsigned short* __restrict__ qb,
    unsigned short* __restrict__ kb,
    unsigned short* __restrict__ vbt)
{
    __shared__ unsigned short As[2 * ASZ];
    __shared__ unsigned short Bs[2 * ASZ];
    int w = blockIdx.x >> 3;
    int col0 = (blockIdx.x & 7) * 128;
    int row0 = blockIdx.y * 128;
    const unsigned short* A  = (w == 0) ? Aq : Akv;
    const unsigned short* BT = (w == 0) ? BTq : (w == 1) ? BTk : BTv;
    void* C  = (w == 0) ? (void*)qb : (w == 1) ? (void*)kb : (void*)vbt;
    int flags = (w == 2) ? 1 : 0;
    gemm_body(As, Bs, A, MD, BT, MD, C, MD, MD, flags, nullptr, row0, col0);
}

// ---------------------------------------------------------------------------
// MFMA flash attention v4: DMA double-buffer (zero-VGPR staging).
//   R2 post-mortem: reg-staged K/V dbuf spilled to scratch (WRITE_SIZE 245MB,
//   VGPR=88 < live set) -> all "overlap" was scratch traffic. Occupancy is
//   GRID-capped at 2 blocks/CU (512 blocks / 256 CU), so LDS is free to spend.
//   - K/V staged via global_load_lds into double-buffered LDS: no VGPRs, the
//     DMA queue holds the in-flight tile. Next chunk issued before compute,
//     drained by the end-of-chunk barrier's implicit vmcnt(0) (GEMM pattern).
//   - XOR bank-swizzle kept, applied by PRE-SWIZZLING the per-lane GLOBAL
//     source address (c8 ^= r&7); LDS dest stays linear as the DMA requires.
//   - Q per-lane in regs (16 VGPRs); defer-max (T13); causal balance remap.
// LDS: 2*16K (Ks) + 2*16K (Vs) + 8K (Ps) = 72 KB -> 2 blocks/CU (= grid cap).
// ---------------------------------------------------------------------------
#define KVB 64

__device__ __forceinline__ void stage_kv(
    unsigned short* KsB, unsigned short* VsB,
    const unsigned short* __restrict__ kbase,
    const unsigned short* __restrict__ vbase, int t0)
{
    int tid = threadIdx.x;
    #pragma unroll
    for (int it = 0; it < 4; it++) {
        int idx = it * 256 + tid;
        int r = idx >> 4, c8 = (idx & 15) ^ (r & 7);   // pre-swizzled source col
        load16_lds(kbase + (size_t)(t0 + r) * MD + c8 * 8, &KsB[idx * 8]);
    }
    #pragma unroll
    for (int it = 0; it < 4; it++) {
        int idx = it * 256 + tid;
        int r = idx >> 3, c8 = (idx & 7) ^ (r & 7);
        load16_lds(vbase + (size_t)r * NT + t0 + c8 * 8, &VsB[idx * 8]);
    }
}

__global__ __launch_bounds__(256) void attn_mfma(
    const unsigned short* __restrict__ qb, const unsigned short* __restrict__ kb,
    const unsigned short* __restrict__ vbt, unsigned short* __restrict__ pr,
    int causal)
{
    __shared__ unsigned short Ks[2][64 * 128];    // [key][d], swizzled
    __shared__ unsigned short Vs[2][128 * 64];    // [d][key], swizzled
    __shared__ unsigned short Ps[4 * 16 * 64];    // per-wave [qrow][key], swizzled

    int tid = threadIdx.x;
    int lane = tid & 63, wave = tid >> 6;
    int lr = lane & 15, quad = lane >> 4;

    int qt, bh;
    if (causal) {
        int bid = blockIdx.x + 16 * blockIdx.y;   // dispatch order, x fastest
        int half = bid >> 8, j = bid & 255;
        qt = half ? (15 - (j & 15)) : (j & 15);
        bh = (half << 4) | (j >> 4);
    } else {
        qt = blockIdx.x; bh = blockIdx.y;
    }
    int b = bh >> 3, h = bh & 7;
    int q0 = qt * 64;
    const float scale = 0.08838834764831845f;  // 1/sqrt(128)

    const unsigned short* kbase = kb + (size_t)(b * NT) * MD + h * HD;
    const unsigned short* vbase = vbt + (size_t)((b * NH + h) * HD) * NT;

    // ---- Q fragments: per-lane direct global load (one-time, L2-hot) ----
    const unsigned short* qrow_p =
        qb + (size_t)(b*NQ + q0 + wave*16 + lr) * MD + h*HD;
    bf16x8 aq[4];
    #pragma unroll
    for (int dk = 0; dk < 4; dk++)
        aq[dk] = *(const bf16x8*)(qrow_p + dk*32 + quad*8);

    // ---- prologue: DMA chunk 0 into buffer 0 ----
    stage_kv(Ks[0], Vs[0], kbase, vbase, 0);

    f32x4 acc[8];
    #pragma unroll
    for (int n = 0; n < 8; n++) acc[n] = (f32x4)0.0f;
    float m_run[4], l_run[4];
    #pragma unroll
    for (int r = 0; r < 4; r++) { m_run[r] = -1e30f; l_run[r] = 0.0f; }

    unsigned short* Pw = &Ps[wave * 16 * 64];
    int nch = causal ? (qt + 1) : (NT / KVB);
    int grow_base = q0 + wave*16 + quad*4;
    int swz = (lr & 7) << 3;   // XOR for rows where (row&7)==(lr&7)

    __syncthreads();           // drains chunk-0 DMA (vmcnt0 + barrier)

    for (int tc = 0; tc < nch; tc++) {
        int cur = tc & 1;
        // issue next-chunk DMA into the other buffer; it stays in flight
        // across the whole compute phase below.
        if (tc + 1 < nch)
            stage_kv(Ks[cur ^ 1], Vs[cur ^ 1], kbase, vbase, (tc + 1) * KVB);

        const unsigned short* Kc = Ks[cur];
        const unsigned short* Vc = Vs[cur];
        int t0 = tc * KVB;

        // ---- QK^T: 4 k-slices of 16 keys, K-dim 128 over 4 dk ----
        f32x4 s[4];
        #pragma unroll
        for (int kt = 0; kt < 4; kt++) s[kt] = (f32x4)0.0f;
        __builtin_amdgcn_s_setprio(1);
        #pragma unroll
        for (int dk = 0; dk < 4; dk++) {
            #pragma unroll
            for (int kt = 0; kt < 4; kt++) {
                bf16x8 bk = *(const bf16x8*)
                    &Kc[(kt*16 + lr) * 128 + ((dk*32 + quad*8) ^ swz)];
                s[kt] = __builtin_amdgcn_mfma_f32_16x16x32_bf16(aq[dk], bk, s[kt], 0, 0, 0);
            }
        }
        __builtin_amdgcn_s_setprio(0);

        // ---- online softmax over 64 keys, defer-max (T13) ----
        float mxt[4];
        #pragma unroll
        for (int r = 0; r < 4; r++) {
            #pragma unroll
            for (int kt = 0; kt < 4; kt++) {
                float x = s[kt][r] * scale;
                if (causal && (t0 + kt*16 + lr > grow_base + r)) x = -1e30f;
                s[kt][r] = x;
            }
            float mx = fmaxf(fmaxf(s[0][r], s[1][r]), fmaxf(s[2][r], s[3][r]));
            #pragma unroll
            for (int off = 1; off < 16; off <<= 1)
                mx = fmaxf(mx, __shfl_xor(mx, off));
            mxt[r] = mx;
        }
        float need = fmaxf(fmaxf(mxt[0]-m_run[0], mxt[1]-m_run[1]),
                           fmaxf(mxt[2]-m_run[2], mxt[3]-m_run[3]));
        if (!__all(need <= 8.0f)) {
            #pragma unroll
            for (int r = 0; r < 4; r++) {
                float mx = fmaxf(mxt[r], m_run[r]);
                float alpha = __expf(m_run[r] - mx);
                m_run[r] = mx;
                l_run[r] *= alpha;
                #pragma unroll
                for (int n = 0; n < 8; n++) acc[n][r] *= alpha;
            }
        }
        #pragma unroll
        for (int r = 0; r < 4; r++) {
            int prow = quad*4 + r;
            int pswz = (prow & 7) << 3;
            float psum = 0.0f;
            #pragma unroll
            for (int kt = 0; kt < 4; kt++) {
                float p = __expf(s[kt][r] - m_run[r]);
                Pw[prow * 64 + ((kt*16 + lr) ^ pswz)] = f2bf(p);
                psum += p;
            }
            #pragma unroll
            for (int off = 1; off < 16; off <<= 1)
                psum += __shfl_xor(psum, off);
            l_run[r] += psum;
        }

        // ---- PV: P (16x64) x V^T fragments ----
        bf16x8 ap0 = *(const bf16x8*)&Pw[lr * 64 + ((quad * 8) ^ swz)];
        bf16x8 ap1 = *(const bf16x8*)&Pw[lr * 64 + ((32 + quad * 8) ^ swz)];
        __builtin_amdgcn_s_setprio(1);
        #pragma unroll
        for (int n = 0; n < 8; n++) {
            bf16x8 bv0 = *(const bf16x8*)
                &Vc[(n*16 + lr) * 64 + ((quad * 8) ^ swz)];
            bf16x8 bv1 = *(const bf16x8*)
                &Vc[(n*16 + lr) * 64 + ((32 + quad * 8) ^ swz)];
            acc[n] = __builtin_amdgcn_mfma_f32_16x16x32_bf16(ap0, bv0, acc[n], 0, 0, 0);
            acc[n] = __builtin_amdgcn_mfma_f32_16x16x32_bf16(ap1, bv1, acc[n], 0, 0, 0);
        }
        __builtin_amdgcn_s_setprio(0);

        // one barrier per chunk: all waves done reading buffers (lgkm) AND
        // the next chunk's DMA drained (vmcnt) -- it had the compute in flight.
        __syncthreads();
    }

    float linv[4];
    #pragma unroll
    for (int r = 0; r < 4; r++) linv[r] = 1.0f / l_run[r];
    #pragma unroll
    for (int n = 0; n < 8; n++) {
        int gcol = h*HD + n*16 + lr;
        #pragma unroll
        for (int r = 0; r < 4; r++) {
            int grow = q0 + wave*16 + quad*4 + r;
            pr[(size_t)(b*NQ + grow) * MD + gcol] = f2bf(acc[n][r] * linv[r]);
        }
    }
}

// ---------------------------------------------------------------------------
extern "C" void kernel_launch(void* const* d_in, const int* in_sizes, int n_in,
                              void* d_out, int out_size, void* d_ws, size_t ws_size,
                              hipStream_t stream)
{
    const float* enc  = (const float*)d_in[0];
    const float* x    = (const float*)d_in[1];
    const float* swq  = (const float*)d_in[5];
    const float* swk  = (const float*)d_in[6];
    const float* swv  = (const float*)d_in[7];
    const float* swo  = (const float*)d_in[8];
    const float* cwq  = (const float*)d_in[9];
    const float* cwk  = (const float*)d_in[10];
    const float* cwv  = (const float*)d_in[11];
    const float* cwo  = (const float*)d_in[12];
    const float* w1   = (const float*)d_in[13];
    const float* b1   = (const float*)d_in[14];
    const float* w2   = (const float*)d_in[15];
    const float* b2   = (const float*)d_in[16];
    const float* ln1g = (const float*)d_in[17];
    const float* ln1b = (const float*)d_in[18];
    const float* ln2g = (const float*)d_in[19];
    const float* ln2b = (const float*)d_in[20];
    const float* ln3g = (const float*)d_in[21];
    const float* ln3b = (const float*)d_in[22];

    float* h = (float*)d_out;
    unsigned short* u = (unsigned short*)d_ws;
    const size_t MW = 1024 * 1024;
    unsigned short* nb   = u;             // 4M ushort
    unsigned short* encb = u + 4*MW;      // 4M
    unsigned short* qb   = u + 8*MW;      // 4M
    unsigned short* kb   = u + 12*MW;     // 4M
    unsigned short* vbt  = u + 16*MW;     // 4M
    unsigned short* pr   = u + 20*MW;     // 4M
    unsigned short* sb   = qb;            // aliases qb..pr (16M), FFN-only
    unsigned short* wb   = u + 24*MW;

    bool upfront = ws_size >= (size_t)240 * MW;

    hipMemcpyAsync(h, x, 4*MW*sizeof(float), hipMemcpyDeviceToDevice, stream);

    dim3 tb(256);
    cast_bf16<<<4096, tb, 0, stream>>>(enc, encb);

    if (upfront) {
        transpose_cast<<<dim3(4,32,48),  tb, 0, stream>>>(swq, wb + 0*MW,  1024, 128);
        transpose_cast<<<dim3(4,32,48),  tb, 0, stream>>>(swk, wb + 6*MW,  1024, 128);
        transpose_cast<<<dim3(4,32,48),  tb, 0, stream>>>(swv, wb + 12*MW, 1024, 128);
        transpose_cast<<<dim3(32,32,6),  tb, 0, stream>>>(swo, wb + 18*MW, 1024, 1024);
        transpose_cast<<<dim3(4,32,48),  tb, 0, stream>>>(cwq, wb + 24*MW, 1024, 128);
        transpose_cast<<<dim3(4,32,48),  tb, 0, stream>>>(cwk, wb + 30*MW, 1024, 128);
        transpose_cast<<<dim3(4,32,48),  tb, 0, stream>>>(cwv, wb + 36*MW, 1024, 128);
        transpose_cast<<<dim3(32,32,6),  tb, 0, stream>>>(cwo, wb + 42*MW, 1024, 1024);
        transpose_cast<<<dim3(128,32,6), tb, 0, stream>>>(w1,  wb + 48*MW, 1024, 4096);
        transpose_cast<<<dim3(32,128,6), tb, 0, stream>>>(w2,  wb + 72*MW, 4096, 1024);
    }

    dim3 gQKV(24, 32), gO(8, 32, 2), gF1(32, 32), gF2(8, 32, 2), gA(16, 32);

    for (int l = 0; l < NL; l++) {
        unsigned short *pwq, *pwk, *pwv, *pwo, *pcq, *pck, *pcv, *pco, *pw1, *pw2;
        if (upfront) {
            pwq = wb + 0*MW  + l*MW;  pwk = wb + 6*MW  + l*MW;
            pwv = wb + 12*MW + l*MW;  pwo = wb + 18*MW + l*MW;
            pcq = wb + 24*MW + l*MW;  pck = wb + 30*MW + l*MW;
            pcv = wb + 36*MW + l*MW;  pco = wb + 42*MW + l*MW;
            pw1 = wb + 48*MW + l*4*MW; pw2 = wb + 72*MW + l*4*MW;
        } else {
            pwq = wb;        pwk = wb + 1*MW; pwv = wb + 2*MW; pwo = wb + 3*MW;
            pcq = wb + 4*MW; pck = wb + 5*MW; pcv = wb + 6*MW; pco = wb + 7*MW;
            pw1 = wb + 8*MW; pw2 = wb + 12*MW;
            transpose_cast<<<dim3(4,32,8),   tb, 0, stream>>>(swq + l*MW,   pwq, 1024, 128);
            transpose_cast<<<dim3(4,32,8),   tb, 0, stream>>>(swk + l*MW,   pwk, 1024, 128);
            transpose_cast<<<dim3(4,32,8),   tb, 0, stream>>>(swv + l*MW,   pwv, 1024, 128);
            transpose_cast<<<dim3(32,32,1),  tb, 0, stream>>>(swo + l*MW,   pwo, 1024, 1024);
            transpose_cast<<<dim3(4,32,8),   tb, 0, stream>>>(cwq + l*MW,   pcq, 1024, 128);
            transpose_cast<<<dim3(4,32,8),   tb, 0, stream>>>(cwk + l*MW,   pck, 1024, 128);
            transpose_cast<<<dim3(4,32,8),   tb, 0, stream>>>(cwv + l*MW,   pcv, 1024, 128);
            transpose_cast<<<dim3(32,32,1),  tb, 0, stream>>>(cwo + l*MW,   pco, 1024, 1024);
            transpose_cast<<<dim3(128,32,1), tb, 0, stream>>>(w1 + l*4*MW,  pw1, 1024, 4096);
            transpose_cast<<<dim3(32,128,1), tb, 0, stream>>>(w2 + l*4*MW,  pw2, 4096, 1024);
        }

        // ---- self attention ----
        ln_kernel<<<ROWS, tb, 0, stream>>>(h, nb, ln1g + l*MD, ln1b + l*MD);
        gemm_qkv<<<gQKV, tb, 0, stream>>>(nb, nb, pwq, pwk, pwv, qb, kb, vbt);
        attn_mfma<<<gA, tb, 0, stream>>>(qb, kb, vbt, pr, 1);
        gemm_bf16<<<gO, tb, 0, stream>>>(pr, MD, pwo, MD, h, MD, 512, 2, nullptr);

        // ---- cross attention ----
        ln_kernel<<<ROWS, tb, 0, stream>>>(h, nb, ln2g + l*MD, ln2b + l*MD);
        gemm_qkv<<<gQKV, tb, 0, stream>>>(nb, encb, pcq, pck, pcv, qb, kb, vbt);
        attn_mfma<<<gA, tb, 0, stream>>>(qb, kb, vbt, pr, 0);
        gemm_bf16<<<gO, tb, 0, stream>>>(pr, MD, pco, MD, h, MD, 512, 2, nullptr);

        // ---- FFN ----
        ln_kernel<<<ROWS, tb, 0, stream>>>(h, nb, ln3g + l*MD, ln3b + l*MD);
        gemm_bf16<<<gF1, tb, 0, stream>>>(nb, MD, pw1, MD, sb, FF, 1024, 4 | 8, b1 + l*FF);
        gemm_bf16<<<gF2, tb, 0, stream>>>(sb, FF, pw2, FF, h, MD, 2048, 2 | 4, b2 + l*MD);
    }
}

// Round 6
// 2853.931 us; speedup vs baseline: 1.2851x; 1.0481x over previous
//
#include <hip/hip_runtime.h>
#include <math.h>

// Problem constants (Decoder_88871463288984)
#define NL 6
#define NH 8
#define MD 1024
#define HD 128
#define FF 4096
#define NB 4
#define NQ 1024
#define NT 1024
#define ROWS (NB*NQ)   // 4096

typedef __attribute__((ext_vector_type(8))) short bf16x8;
typedef __attribute__((ext_vector_type(4))) float f32x4;

// fp32 -> bf16, round-to-nearest-even
__device__ __forceinline__ unsigned short f2bf(float f) {
    unsigned int u = __float_as_uint(f);
    u += 0x7fffu + ((u >> 16) & 1u);
    return (unsigned short)(u >> 16);
}

// async global->LDS, 16 bytes per lane (dst must be wave-uniform base + lane*16)
__device__ __forceinline__ void load16_lds(const unsigned short* g, unsigned short* l) {
    __builtin_amdgcn_global_load_lds(
        (const __attribute__((address_space(1))) unsigned int*)g,
        (__attribute__((address_space(3))) unsigned int*)l, 16, 0, 0);
}

// ---------------------------------------------------------------------------
// LayerNorm: fp32 in (h), bf16 out. One block per row of 1024.
// ---------------------------------------------------------------------------
__global__ __launch_bounds__(256) void ln_kernel(
    const float* __restrict__ x, unsigned short* __restrict__ y,
    const float* __restrict__ g, const float* __restrict__ b)
{
    __shared__ float sdata[8];
    int row = blockIdx.x;
    int tid = threadIdx.x;
    const float* xr = x + (size_t)row * MD;
    float4 v = ((const float4*)xr)[tid];
    float s = v.x + v.y + v.z + v.w;
    #pragma unroll
    for (int o = 32; o > 0; o >>= 1) s += __shfl_down(s, o, 64);
    if ((tid & 63) == 0) sdata[tid >> 6] = s;
    __syncthreads();
    if (tid == 0) sdata[4] = sdata[0] + sdata[1] + sdata[2] + sdata[3];
    __syncthreads();
    float mean = sdata[4] * (1.0f / MD);
    float4 d = make_float4(v.x - mean, v.y - mean, v.z - mean, v.w - mean);
    float sq = d.x*d.x + d.y*d.y + d.z*d.z + d.w*d.w;
    #pragma unroll
    for (int o = 32; o > 0; o >>= 1) sq += __shfl_down(sq, o, 64);
    __syncthreads();
    if ((tid & 63) == 0) sdata[tid >> 6] = sq;
    __syncthreads();
    if (tid == 0) sdata[4] = sdata[0] + sdata[1] + sdata[2] + sdata[3];
    __syncthreads();
    float var = sdata[4] * (1.0f / MD);
    float rstd = rsqrtf(var + 1e-5f);
    float4 g4 = ((const float4*)g)[tid];
    float4 b4 = ((const float4*)b)[tid];
    ushort4 o;
    o.x = f2bf(d.x * rstd * g4.x + b4.x);
    o.y = f2bf(d.y * rstd * g4.y + b4.y);
    o.z = f2bf(d.z * rstd * g4.z + b4.z);
    o.w = f2bf(d.w * rstd * g4.w + b4.w);
    *(ushort4*)(y + (size_t)row * MD + tid * 4) = o;
}

// ---------------------------------------------------------------------------
// fp32 -> bf16 cast (enc_out). n = grid*256*4 elements exactly.
// ---------------------------------------------------------------------------
__global__ __launch_bounds__(256) void cast_bf16(
    const float* __restrict__ x, unsigned short* __restrict__ y)
{
    int i = blockIdx.x * 256 + threadIdx.x;
    float4 v = ((const float4*)x)[i];
    ushort4 o;
    o.x = f2bf(v.x); o.y = f2bf(v.y); o.z = f2bf(v.z); o.w = f2bf(v.w);
    ((ushort4*)y)[i] = o;
}

// ---------------------------------------------------------------------------
// Batched transpose + cast: X fp32 (batch,R,C) -> Y bf16 (batch,C,R).
// ---------------------------------------------------------------------------
__global__ __launch_bounds__(256) void transpose_cast(
    const float* __restrict__ X, unsigned short* __restrict__ Y, int R, int C)
{
    __shared__ float tile[32][33];
    int bz = blockIdx.z;
    int r0 = blockIdx.y * 32, c0 = blockIdx.x * 32;
    const float* Xb = X + (size_t)bz * R * C;
    unsigned short* Yb = Y + (size_t)bz * R * C;
    int tx = threadIdx.x & 31, ty = threadIdx.x >> 5;
    #pragma unroll
    for (int i = 0; i < 4; i++)
        tile[ty + i*8][tx] = Xb[(size_t)(r0 + ty + i*8) * C + c0 + tx];
    __syncthreads();
    #pragma unroll
    for (int i = 0; i < 4; i++)
        Yb[(size_t)(c0 + ty + i*8) * R + r0 + tx] = f2bf(tile[tx][ty + i*8]);
}

// ---------------------------------------------------------------------------
// Shared bf16 MFMA GEMM body, DOUBLE-BUFFERED single-barrier K-loop.
// Tile 128x128, BK=64, 4 waves x (4x4) 16x16x32, fp32 accum.
// R4: XOR bank-swizzle on As/Bs (16B-segment ^ row&7). Unswizzled, the
// 128-B row stride put all 16 lanes of a quad on the same 4-bank group
// (16-way conflict, 9.4M extra cyc/dispatch = ~24 cyc extra per ds_read).
// Swizzle applied DMA-compatibly: pre-swizzled GLOBAL source column in
// stage_tiles (LDS dest stays linear), matching XOR on the ds_read offset
// (row&7 == lr&7 for fragment rows). Same fix that won on attn K/V in R4.
// flags: 1 = write V^T layout (b,h,d,t) bf16
//        2 = fp32 atomicAdd into Cout (residual / split-K accumulate)
//        4 = add bias[col]
//        8 = ReLU
// ---------------------------------------------------------------------------
#define BKK 64
#define ASZ (128 * BKK)

__device__ __forceinline__ void stage_tiles(
    unsigned short* As, unsigned short* Bs,
    const unsigned short* __restrict__ A, int lda,
    const unsigned short* __restrict__ BT, int ldb,
    int row0, int col0, int kt)
{
    int tid = threadIdx.x;
    #pragma unroll
    for (int it = 0; it < 4; it++) {
        int idx = it * 256 + tid;
        int r = idx >> 3, c8 = (idx & 7) ^ (r & 7);   // pre-swizzled source seg
        load16_lds(A + (size_t)(row0 + r) * lda + kt + c8 * 8, &As[idx * 8]);
    }
    #pragma unroll
    for (int it = 0; it < 4; it++) {
        int idx = it * 256 + tid;
        int r = idx >> 3, c8 = (idx & 7) ^ (r & 7);
        load16_lds(BT + (size_t)(col0 + r) * ldb + kt + c8 * 8, &Bs[idx * 8]);
    }
}

__device__ __forceinline__ void gemm_body(
    unsigned short* As, unsigned short* Bs,
    const unsigned short* __restrict__ A, int lda,
    const unsigned short* __restrict__ BT, int ldb,
    void* __restrict__ Cout, int ldc, int Kdim, int flags,
    const float* __restrict__ bias, int row0, int col0)
{
    int tid = threadIdx.x;
    int lane = tid & 63;
    int wave = tid >> 6;
    int mr = (wave & 1) * 64;
    int nc = (wave >> 1) * 64;
    int lr = lane & 15;
    int quad = lane >> 4;
    int swz = (lr & 7) << 3;          // fragment row&7 == lr&7

    f32x4 acc[4][4];
    #pragma unroll
    for (int i = 0; i < 4; i++)
        #pragma unroll
        for (int j = 0; j < 4; j++) acc[i][j] = (f32x4)0.0f;

    const int NKi = Kdim >> 6;
    // prologue: stage k=0 into buffer 0, wait
    stage_tiles(As, Bs, A, lda, BT, ldb, row0, col0, 0);
    __syncthreads();

    for (int k = 0; k < NKi; k++) {
        unsigned short* cA = As + (k & 1) * ASZ;
        unsigned short* cB = Bs + (k & 1) * ASZ;
        // issue next-tile DMA first; it overlaps this iteration's compute.
        if (k + 1 < NKi)
            stage_tiles(As + ((k + 1) & 1) * ASZ, Bs + ((k + 1) & 1) * ASZ,
                        A, lda, BT, ldb, row0, col0, (k + 1) * BKK);
        #pragma unroll
        for (int ks = 0; ks < 2; ks++) {
            bf16x8 af[4], bfr[4];
            #pragma unroll
            for (int i = 0; i < 4; i++)
                af[i] = *(const bf16x8*)
                    &cA[(mr + i*16 + lr) * BKK + ((ks*32 + quad*8) ^ swz)];
            #pragma unroll
            for (int j = 0; j < 4; j++)
                bfr[j] = *(const bf16x8*)
                    &cB[(nc + j*16 + lr) * BKK + ((ks*32 + quad*8) ^ swz)];
            #pragma unroll
            for (int i = 0; i < 4; i++)
                #pragma unroll
                for (int j = 0; j < 4; j++)
                    acc[i][j] = __builtin_amdgcn_mfma_f32_16x16x32_bf16(
                        af[i], bfr[j], acc[i][j], 0, 0, 0);
        }
        // one barrier per iter: waits compute ds_reads (lgkm) AND the k+1
        // stage DMA (vmcnt) -- which has had the whole compute phase in flight.
        __syncthreads();
    }

    float bvj[4];
    if (flags & 4) {
        #pragma unroll
        for (int j = 0; j < 4; j++) bvj[j] = bias[col0 + nc + j*16 + lr];
    } else {
        #pragma unroll
        for (int j = 0; j < 4; j++) bvj[j] = 0.0f;
    }

    if (flags & 1) {
        // V^T store: vbt[((b*8+h)*128 + d) * NT + t], 4 consecutive t packed
        unsigned short* V = (unsigned short*)Cout;
        #pragma unroll
        for (int i = 0; i < 4; i++) {
            int grow0 = row0 + mr + i*16 + quad*4;
            int bb = grow0 >> 10, tt = grow0 & 1023;
            #pragma unroll
            for (int j = 0; j < 4; j++) {
                int gcol = col0 + nc + j*16 + lr;
                int hh = gcol >> 7, dd = gcol & 127;
                ushort4 pk;
                pk.x = f2bf(acc[i][j][0]); pk.y = f2bf(acc[i][j][1]);
                pk.z = f2bf(acc[i][j][2]); pk.w = f2bf(acc[i][j][3]);
                *(ushort4*)(V + (((size_t)(bb*NH + hh)*HD + dd) * NT + tt)) = pk;
            }
        }
    } else if (flags & 2) {
        float* Cf = (float*)Cout;
        #pragma unroll
        for (int i = 0; i < 4; i++) {
            int grow0 = row0 + mr + i*16 + quad*4;
            #pragma unroll
            for (int j = 0; j < 4; j++) {
                int gcol = col0 + nc + j*16 + lr;
                #pragma unroll
                for (int r = 0; r < 4; r++) {
                    float v = acc[i][j][r] + bvj[j];
                    atomicAdd(&Cf[(size_t)(grow0 + r) * ldc + gcol], v);
                }
            }
        }
    } else {
        unsigned short* Cb = (unsigned short*)Cout;
        #pragma unroll
        for (int i = 0; i < 4; i++) {
            int grow0 = row0 + mr + i*16 + quad*4;
            #pragma unroll
            for (int j = 0; j < 4; j++) {
                int gcol = col0 + nc + j*16 + lr;
                #pragma unroll
                for (int r = 0; r < 4; r++) {
                    float v = acc[i][j][r] + bvj[j];
                    if (flags & 8) v = fmaxf(v, 0.0f);
                    Cb[(size_t)(grow0 + r) * ldc + gcol] = f2bf(v);
                }
            }
        }
    }
}

// Generic GEMM with K-split over blockIdx.z (Kper = K per split).
__global__ __launch_bounds__(256) void gemm_bf16(
    const unsigned short* __restrict__ A, int lda,
    const unsigned short* __restrict__ BT, int ldb,
    void* __restrict__ Cout, int ldc, int Kper, int flags,
    const float* __restrict__ bias)
{
    __shared__ unsigned short As[2 * ASZ];
    __shared__ unsigned short Bs[2 * ASZ];
    int row0 = blockIdx.y * 128, col0 = blockIdx.x * 128;
    int kbase = blockIdx.z * Kper;
    if (blockIdx.z) flags &= ~4;      // bias only once
    gemm_body(As, Bs, A + kbase, lda, BT + kbase, ldb, Cout, ldc,
              Kper, flags, bias, row0, col0);
}

// Fused Q/K/V projection: blockIdx.x in [0,24): weight = x>>3, col = (x&7)*128.
// Q uses Aq, K/V use Akv. V output goes to V^T layout.
__global__ __launch_bounds__(256) void gemm_qkv(
    const unsigned short* __restrict__ Aq,
    const unsigned short* __restrict__ Akv,
    const unsigned short* __restrict__ BTq,
    const unsigned short* __restrict__ BTk,
    const unsigned short* __restrict__ BTv,
    unsigned short* __restrict__ qb,
    unsigned short* __restrict__ kb,
    unsigned short* __restrict__ vbt)
{
    __shared__ unsigned short As[2 * ASZ];
    __shared__ unsigned short Bs[2 * ASZ];
    int w = blockIdx.x >> 3;
    int col0 = (blockIdx.x & 7) * 128;
    int row0 = blockIdx.y * 128;
    const unsigned short* A  = (w == 0) ? Aq : Akv;
    const unsigned short* BT = (w == 0) ? BTq : (w == 1) ? BTk : BTv;
    void* C  = (w == 0) ? (void*)qb : (w == 1) ? (void*)kb : (void*)vbt;
    int flags = (w == 2) ? 1 : 0;
    gemm_body(As, Bs, A, MD, BT, MD, C, MD, MD, flags, nullptr, row0, col0);
}

// ---------------------------------------------------------------------------
// MFMA flash attention v4: DMA double-buffer (zero-VGPR staging). Verified
// in R4 (attn no longer in top-5 dispatches). Unchanged this round.
// ---------------------------------------------------------------------------
#define KVB 64

__device__ __forceinline__ void stage_kv(
    unsigned short* KsB, unsigned short* VsB,
    const unsigned short* __restrict__ kbase,
    const unsigned short* __restrict__ vbase, int t0)
{
    int tid = threadIdx.x;
    #pragma unroll
    for (int it = 0; it < 4; it++) {
        int idx = it * 256 + tid;
        int r = idx >> 4, c8 = (idx & 15) ^ (r & 7);   // pre-swizzled source col
        load16_lds(kbase + (size_t)(t0 + r) * MD + c8 * 8, &KsB[idx * 8]);
    }
    #pragma unroll
    for (int it = 0; it < 4; it++) {
        int idx = it * 256 + tid;
        int r = idx >> 3, c8 = (idx & 7) ^ (r & 7);
        load16_lds(vbase + (size_t)r * NT + t0 + c8 * 8, &VsB[idx * 8]);
    }
}

__global__ __launch_bounds__(256) void attn_mfma(
    const unsigned short* __restrict__ qb, const unsigned short* __restrict__ kb,
    const unsigned short* __restrict__ vbt, unsigned short* __restrict__ pr,
    int causal)
{
    __shared__ unsigned short Ks[2][64 * 128];    // [key][d], swizzled
    __shared__ unsigned short Vs[2][128 * 64];    // [d][key], swizzled
    __shared__ unsigned short Ps[4 * 16 * 64];    // per-wave [qrow][key], swizzled

    int tid = threadIdx.x;
    int lane = tid & 63, wave = tid >> 6;
    int lr = lane & 15, quad = lane >> 4;

    int qt, bh;
    if (causal) {
        int bid = blockIdx.x + 16 * blockIdx.y;   // dispatch order, x fastest
        int half = bid >> 8, j = bid & 255;
        qt = half ? (15 - (j & 15)) : (j & 15);
        bh = (half << 4) | (j >> 4);
    } else {
        qt = blockIdx.x; bh = blockIdx.y;
    }
    int b = bh >> 3, h = bh & 7;
    int q0 = qt * 64;
    const float scale = 0.08838834764831845f;  // 1/sqrt(128)

    const unsigned short* kbase = kb + (size_t)(b * NT) * MD + h * HD;
    const unsigned short* vbase = vbt + (size_t)((b * NH + h) * HD) * NT;

    // ---- Q fragments: per-lane direct global load (one-time, L2-hot) ----
    const unsigned short* qrow_p =
        qb + (size_t)(b*NQ + q0 + wave*16 + lr) * MD + h*HD;
    bf16x8 aq[4];
    #pragma unroll
    for (int dk = 0; dk < 4; dk++)
        aq[dk] = *(const bf16x8*)(qrow_p + dk*32 + quad*8);

    // ---- prologue: DMA chunk 0 into buffer 0 ----
    stage_kv(Ks[0], Vs[0], kbase, vbase, 0);

    f32x4 acc[8];
    #pragma unroll
    for (int n = 0; n < 8; n++) acc[n] = (f32x4)0.0f;
    float m_run[4], l_run[4];
    #pragma unroll
    for (int r = 0; r < 4; r++) { m_run[r] = -1e30f; l_run[r] = 0.0f; }

    unsigned short* Pw = &Ps[wave * 16 * 64];
    int nch = causal ? (qt + 1) : (NT / KVB);
    int grow_base = q0 + wave*16 + quad*4;
    int swz = (lr & 7) << 3;   // XOR for rows where (row&7)==(lr&7)

    __syncthreads();           // drains chunk-0 DMA (vmcnt0 + barrier)

    for (int tc = 0; tc < nch; tc++) {
        int cur = tc & 1;
        // issue next-chunk DMA into the other buffer; it stays in flight
        // across the whole compute phase below.
        if (tc + 1 < nch)
            stage_kv(Ks[cur ^ 1], Vs[cur ^ 1], kbase, vbase, (tc + 1) * KVB);

        const unsigned short* Kc = Ks[cur];
        const unsigned short* Vc = Vs[cur];
        int t0 = tc * KVB;

        // ---- QK^T: 4 k-slices of 16 keys, K-dim 128 over 4 dk ----
        f32x4 s[4];
        #pragma unroll
        for (int kt = 0; kt < 4; kt++) s[kt] = (f32x4)0.0f;
        __builtin_amdgcn_s_setprio(1);
        #pragma unroll
        for (int dk = 0; dk < 4; dk++) {
            #pragma unroll
            for (int kt = 0; kt < 4; kt++) {
                bf16x8 bk = *(const bf16x8*)
                    &Kc[(kt*16 + lr) * 128 + ((dk*32 + quad*8) ^ swz)];
                s[kt] = __builtin_amdgcn_mfma_f32_16x16x32_bf16(aq[dk], bk, s[kt], 0, 0, 0);
            }
        }
        __builtin_amdgcn_s_setprio(0);

        // ---- online softmax over 64 keys, defer-max (T13) ----
        float mxt[4];
        #pragma unroll
        for (int r = 0; r < 4; r++) {
            #pragma unroll
            for (int kt = 0; kt < 4; kt++) {
                float x = s[kt][r] * scale;
                if (causal && (t0 + kt*16 + lr > grow_base + r)) x = -1e30f;
                s[kt][r] = x;
            }
            float mx = fmaxf(fmaxf(s[0][r], s[1][r]), fmaxf(s[2][r], s[3][r]));
            #pragma unroll
            for (int off = 1; off < 16; off <<= 1)
                mx = fmaxf(mx, __shfl_xor(mx, off));
            mxt[r] = mx;
        }
        float need = fmaxf(fmaxf(mxt[0]-m_run[0], mxt[1]-m_run[1]),
                           fmaxf(mxt[2]-m_run[2], mxt[3]-m_run[3]));
        if (!__all(need <= 8.0f)) {
            #pragma unroll
            for (int r = 0; r < 4; r++) {
                float mx = fmaxf(mxt[r], m_run[r]);
                float alpha = __expf(m_run[r] - mx);
                m_run[r] = mx;
                l_run[r] *= alpha;
                #pragma unroll
                for (int n = 0; n < 8; n++) acc[n][r] *= alpha;
            }
        }
        #pragma unroll
        for (int r = 0; r < 4; r++) {
            int prow = quad*4 + r;
            int pswz = (prow & 7) << 3;
            float psum = 0.0f;
            #pragma unroll
            for (int kt = 0; kt < 4; kt++) {
                float p = __expf(s[kt][r] - m_run[r]);
                Pw[prow * 64 + ((kt*16 + lr) ^ pswz)] = f2bf(p);
                psum += p;
            }
            #pragma unroll
            for (int off = 1; off < 16; off <<= 1)
                psum += __shfl_xor(psum, off);
            l_run[r] += psum;
        }

        // ---- PV: P (16x64) x V^T fragments ----
        bf16x8 ap0 = *(const bf16x8*)&Pw[lr * 64 + ((quad * 8) ^ swz)];
        bf16x8 ap1 = *(const bf16x8*)&Pw[lr * 64 + ((32 + quad * 8) ^ swz)];
        __builtin_amdgcn_s_setprio(1);
        #pragma unroll
        for (int n = 0; n < 8; n++) {
            bf16x8 bv0 = *(const bf16x8*)
                &Vc[(n*16 + lr) * 64 + ((quad * 8) ^ swz)];
            bf16x8 bv1 = *(const bf16x8*)
                &Vc[(n*16 + lr) * 64 + ((32 + quad * 8) ^ swz)];
            acc[n] = __builtin_amdgcn_mfma_f32_16x16x32_bf16(ap0, bv0, acc[n], 0, 0, 0);
            acc[n] = __builtin_amdgcn_mfma_f32_16x16x32_bf16(ap1, bv1, acc[n], 0, 0, 0);
        }
        __builtin_amdgcn_s_setprio(0);

        // one barrier per chunk: all waves done reading buffers (lgkm) AND
        // the next chunk's DMA drained (vmcnt) -- it had the compute in flight.
        __syncthreads();
    }

    float linv[4];
    #pragma unroll
    for (int r = 0; r < 4; r++) linv[r] = 1.0f / l_run[r];
    #pragma unroll
    for (int n = 0; n < 8; n++) {
        int gcol = h*HD + n*16 + lr;
        #pragma unroll
        for (int r = 0; r < 4; r++) {
            int grow = q0 + wave*16 + quad*4 + r;
            pr[(size_t)(b*NQ + grow) * MD + gcol] = f2bf(acc[n][r] * linv[r]);
        }
    }
}

// ---------------------------------------------------------------------------
extern "C" void kernel_launch(void* const* d_in, const int* in_sizes, int n_in,
                              void* d_out, int out_size, void* d_ws, size_t ws_size,
                              hipStream_t stream)
{
    const float* enc  = (const float*)d_in[0];
    const float* x    = (const float*)d_in[1];
    const float* swq  = (const float*)d_in[5];
    const float* swk  = (const float*)d_in[6];
    const float* swv  = (const float*)d_in[7];
    const float* swo  = (const float*)d_in[8];
    const float* cwq  = (const float*)d_in[9];
    const float* cwk  = (const float*)d_in[10];
    const float* cwv  = (const float*)d_in[11];
    const float* cwo  = (const float*)d_in[12];
    const float* w1   = (const float*)d_in[13];
    const float* b1   = (const float*)d_in[14];
    const float* w2   = (const float*)d_in[15];
    const float* b2   = (const float*)d_in[16];
    const float* ln1g = (const float*)d_in[17];
    const float* ln1b = (const float*)d_in[18];
    const float* ln2g = (const float*)d_in[19];
    const float* ln2b = (const float*)d_in[20];
    const float* ln3g = (const float*)d_in[21];
    const float* ln3b = (const float*)d_in[22];

    float* h = (float*)d_out;
    unsigned short* u = (unsigned short*)d_ws;
    const size_t MW = 1024 * 1024;
    unsigned short* nb   = u;             // 4M ushort
    unsigned short* encb = u + 4*MW;      // 4M
    unsigned short* qb   = u + 8*MW;      // 4M
    unsigned short* kb   = u + 12*MW;     // 4M
    unsigned short* vbt  = u + 16*MW;     // 4M
    unsigned short* pr   = u + 20*MW;     // 4M
    unsigned short* sb   = qb;            // aliases qb..pr (16M), FFN-only
    unsigned short* wb   = u + 24*MW;

    bool upfront = ws_size >= (size_t)240 * MW;

    hipMemcpyAsync(h, x, 4*MW*sizeof(float), hipMemcpyDeviceToDevice, stream);

    dim3 tb(256);
    cast_bf16<<<4096, tb, 0, stream>>>(enc, encb);

    if (upfront) {
        transpose_cast<<<dim3(4,32,48),  tb, 0, stream>>>(swq, wb + 0*MW,  1024, 128);
        transpose_cast<<<dim3(4,32,48),  tb, 0, stream>>>(swk, wb + 6*MW,  1024, 128);
        transpose_cast<<<dim3(4,32,48),  tb, 0, stream>>>(swv, wb + 12*MW, 1024, 128);
        transpose_cast<<<dim3(32,32,6),  tb, 0, stream>>>(swo, wb + 18*MW, 1024, 1024);
        transpose_cast<<<dim3(4,32,48),  tb, 0, stream>>>(cwq, wb + 24*MW, 1024, 128);
        transpose_cast<<<dim3(4,32,48),  tb, 0, stream>>>(cwk, wb + 30*MW, 1024, 128);
        transpose_cast<<<dim3(4,32,48),  tb, 0, stream>>>(cwv, wb + 36*MW, 1024, 128);
        transpose_cast<<<dim3(32,32,6),  tb, 0, stream>>>(cwo, wb + 42*MW, 1024, 1024);
        transpose_cast<<<dim3(128,32,6), tb, 0, stream>>>(w1,  wb + 48*MW, 1024, 4096);
        transpose_cast<<<dim3(32,128,6), tb, 0, stream>>>(w2,  wb + 72*MW, 4096, 1024);
    }

    dim3 gQKV(24, 32), gO(8, 32, 2), gF1(32, 32), gF2(8, 32, 2), gA(16, 32);

    for (int l = 0; l < NL; l++) {
        unsigned short *pwq, *pwk, *pwv, *pwo, *pcq, *pck, *pcv, *pco, *pw1, *pw2;
        if (upfront) {
            pwq = wb + 0*MW  + l*MW;  pwk = wb + 6*MW  + l*MW;
            pwv = wb + 12*MW + l*MW;  pwo = wb + 18*MW + l*MW;
            pcq = wb + 24*MW + l*MW;  pck = wb + 30*MW + l*MW;
            pcv = wb + 36*MW + l*MW;  pco = wb + 42*MW + l*MW;
            pw1 = wb + 48*MW + l*4*MW; pw2 = wb + 72*MW + l*4*MW;
        } else {
            pwq = wb;        pwk = wb + 1*MW; pwv = wb + 2*MW; pwo = wb + 3*MW;
            pcq = wb + 4*MW; pck = wb + 5*MW; pcv = wb + 6*MW; pco = wb + 7*MW;
            pw1 = wb + 8*MW; pw2 = wb + 12*MW;
            transpose_cast<<<dim3(4,32,8),   tb, 0, stream>>>(swq + l*MW,   pwq, 1024, 128);
            transpose_cast<<<dim3(4,32,8),   tb, 0, stream>>>(swk + l*MW,   pwk, 1024, 128);
            transpose_cast<<<dim3(4,32,8),   tb, 0, stream>>>(swv + l*MW,   pwv, 1024, 128);
            transpose_cast<<<dim3(32,32,1),  tb, 0, stream>>>(swo + l*MW,   pwo, 1024, 1024);
            transpose_cast<<<dim3(4,32,8),   tb, 0, stream>>>(cwq + l*MW,   pcq, 1024, 128);
            transpose_cast<<<dim3(4,32,8),   tb, 0, stream>>>(cwk + l*MW,   pck, 1024, 128);
            transpose_cast<<<dim3(4,32,8),   tb, 0, stream>>>(cwv + l*MW,   pcv, 1024, 128);
            transpose_cast<<<dim3(32,32,1),  tb, 0, stream>>>(cwo + l*MW,   pco, 1024, 1024);
            transpose_cast<<<dim3(128,32,1), tb, 0, stream>>>(w1 + l*4*MW,  pw1, 1024, 4096);
            transpose_cast<<<dim3(32,128,1), tb, 0, stream>>>(w2 + l*4*MW,  pw2, 4096, 1024);
        }

        // ---- self attention ----
        ln_kernel<<<ROWS, tb, 0, stream>>>(h, nb, ln1g + l*MD, ln1b + l*MD);
        gemm_qkv<<<gQKV, tb, 0, stream>>>(nb, nb, pwq, pwk, pwv, qb, kb, vbt);
        attn_mfma<<<gA, tb, 0, stream>>>(qb, kb, vbt, pr, 1);
        gemm_bf16<<<gO, tb, 0, stream>>>(pr, MD, pwo, MD, h, MD, 512, 2, nullptr);

        // ---- cross attention ----
        ln_kernel<<<ROWS, tb, 0, stream>>>(h, nb, ln2g + l*MD, ln2b + l*MD);
        gemm_qkv<<<gQKV, tb, 0, stream>>>(nb, encb, pcq, pck, pcv, qb, kb, vbt);
        attn_mfma<<<gA, tb, 0, stream>>>(qb, kb, vbt, pr, 0);
        gemm_bf16<<<gO, tb, 0, stream>>>(pr, MD, pco, MD, h, MD, 512, 2, nullptr);

        // ---- FFN ----
        ln_kernel<<<ROWS, tb, 0, stream>>>(h, nb, ln3g + l*MD, ln3b + l*MD);
        gemm_bf16<<<gF1, tb, 0, stream>>>(nb, MD, pw1, MD, sb, FF, 1024, 4 | 8, b1 + l*FF);
        gemm_bf16<<<gF2, tb, 0, stream>>>(sb, FF, pw2, FF, h, MD, 2048, 2 | 4, b2 + l*MD);
    }
}

// Round 10
// 2787.860 us; speedup vs baseline: 1.3155x; 1.0237x over previous
//
#include <hip/hip_runtime.h>
#include <math.h>

// Problem constants (Decoder_88871463288984)
#define NL 6
#define NH 8
#define MD 1024
#define HD 128
#define FF 4096
#define NB 4
#define NQ 1024
#define NT 1024
#define ROWS (NB*NQ)   // 4096

typedef __attribute__((ext_vector_type(8))) short bf16x8;
typedef __attribute__((ext_vector_type(4))) float f32x4;

// fp32 -> bf16, round-to-nearest-even
__device__ __forceinline__ unsigned short f2bf(float f) {
    unsigned int u = __float_as_uint(f);
    u += 0x7fffu + ((u >> 16) & 1u);
    return (unsigned short)(u >> 16);
}

// async global->LDS, 16 bytes per lane (dst must be wave-uniform base + lane*16)
__device__ __forceinline__ void load16_lds(const unsigned short* g, unsigned short* l) {
    __builtin_amdgcn_global_load_lds(
        (const __attribute__((address_space(1))) unsigned int*)g,
        (__attribute__((address_space(3))) unsigned int*)l, 16, 0, 0);
}

// ---------------------------------------------------------------------------
// LayerNorm: fp32 in (h), bf16 out. One block per row of 1024.
// ---------------------------------------------------------------------------
__global__ __launch_bounds__(256) void ln_kernel(
    const float* __restrict__ x, unsigned short* __restrict__ y,
    const float* __restrict__ g, const float* __restrict__ b)
{
    __shared__ float sdata[8];
    int row = blockIdx.x;
    int tid = threadIdx.x;
    const float* xr = x + (size_t)row * MD;
    float4 v = ((const float4*)xr)[tid];
    float s = v.x + v.y + v.z + v.w;
    #pragma unroll
    for (int o = 32; o > 0; o >>= 1) s += __shfl_down(s, o, 64);
    if ((tid & 63) == 0) sdata[tid >> 6] = s;
    __syncthreads();
    if (tid == 0) sdata[4] = sdata[0] + sdata[1] + sdata[2] + sdata[3];
    __syncthreads();
    float mean = sdata[4] * (1.0f / MD);
    float4 d = make_float4(v.x - mean, v.y - mean, v.z - mean, v.w - mean);
    float sq = d.x*d.x + d.y*d.y + d.z*d.z + d.w*d.w;
    #pragma unroll
    for (int o = 32; o > 0; o >>= 1) sq += __shfl_down(sq, o, 64);
    __syncthreads();
    if ((tid & 63) == 0) sdata[tid >> 6] = sq;
    __syncthreads();
    if (tid == 0) sdata[4] = sdata[0] + sdata[1] + sdata[2] + sdata[3];
    __syncthreads();
    float var = sdata[4] * (1.0f / MD);
    float rstd = rsqrtf(var + 1e-5f);
    float4 g4 = ((const float4*)g)[tid];
    float4 b4 = ((const float4*)b)[tid];
    ushort4 o;
    o.x = f2bf(d.x * rstd * g4.x + b4.x);
    o.y = f2bf(d.y * rstd * g4.y + b4.y);
    o.z = f2bf(d.z * rstd * g4.z + b4.z);
    o.w = f2bf(d.w * rstd * g4.w + b4.w);
    *(ushort4*)(y + (size_t)row * MD + tid * 4) = o;
}

// ---------------------------------------------------------------------------
// fp32 -> bf16 cast (enc_out). n = grid*256*4 elements exactly.
// ---------------------------------------------------------------------------
__global__ __launch_bounds__(256) void cast_bf16(
    const float* __restrict__ x, unsigned short* __restrict__ y)
{
    int i = blockIdx.x * 256 + threadIdx.x;
    float4 v = ((const float4*)x)[i];
    ushort4 o;
    o.x = f2bf(v.x); o.y = f2bf(v.y); o.z = f2bf(v.z); o.w = f2bf(v.w);
    ((ushort4*)y)[i] = o;
}

// ---------------------------------------------------------------------------
// Batched transpose + cast: X fp32 (batch,R,C) -> Y bf16 (batch,C,R).
// ---------------------------------------------------------------------------
__global__ __launch_bounds__(256) void transpose_cast(
    const float* __restrict__ X, unsigned short* __restrict__ Y, int R, int C)
{
    __shared__ float tile[32][33];
    int bz = blockIdx.z;
    int r0 = blockIdx.y * 32, c0 = blockIdx.x * 32;
    const float* Xb = X + (size_t)bz * R * C;
    unsigned short* Yb = Y + (size_t)bz * R * C;
    int tx = threadIdx.x & 31, ty = threadIdx.x >> 5;
    #pragma unroll
    for (int i = 0; i < 4; i++)
        tile[ty + i*8][tx] = Xb[(size_t)(r0 + ty + i*8) * C + c0 + tx];
    __syncthreads();
    #pragma unroll
    for (int i = 0; i < 4; i++)
        Yb[(size_t)(c0 + ty + i*8) * R + r0 + tx] = f2bf(tile[tx][ty + i*8]);
}

// ---------------------------------------------------------------------------
// Shared bf16 MFMA GEMM body. Tile 128x128, BK=64, 4 waves x (4x4) 16x16x32.
// R4: XOR bank-swizzle (verified R6: SQ_LDS_BANK_CONFLICT 9.4M -> 0).
// R6: counted-vmcnt two-barrier K-loop (T4). The old __syncthreads emitted
// s_waitcnt vmcnt(0), draining the NEXT tile's DMA every iteration (the m97
// ~20% stall). New schedule per iteration:
//   issue stage(k+1); vmcnt(8) [oldest 8 = stage(k), in-order retirement];
//   s_barrier [all waves' stage(k) arrived]; ds_read+MFMA;
//   lgkmcnt(0); s_barrier [all waves done reading buf k before stage(k+2)
//   overwrites it]. stage(k+1) stays in flight across the whole compute.
// flags: 1 = write V^T layout (b,h,d,t) bf16
//        2 = fp32 atomicAdd into Cout (residual / split-K accumulate)
//        4 = add bias[col]
//        8 = ReLU
// ---------------------------------------------------------------------------
#define BKK 64
#define ASZ (128 * BKK)

__device__ __forceinline__ void stage_tiles(
    unsigned short* As, unsigned short* Bs,
    const unsigned short* __restrict__ A, int lda,
    const unsigned short* __restrict__ BT, int ldb,
    int row0, int col0, int kt)
{
    int tid = threadIdx.x;
    #pragma unroll
    for (int it = 0; it < 4; it++) {
        int idx = it * 256 + tid;
        int r = idx >> 3, c8 = (idx & 7) ^ (r & 7);   // pre-swizzled source seg
        load16_lds(A + (size_t)(row0 + r) * lda + kt + c8 * 8, &As[idx * 8]);
    }
    #pragma unroll
    for (int it = 0; it < 4; it++) {
        int idx = it * 256 + tid;
        int r = idx >> 3, c8 = (idx & 7) ^ (r & 7);
        load16_lds(BT + (size_t)(col0 + r) * ldb + kt + c8 * 8, &Bs[idx * 8]);
    }
}

__device__ __forceinline__ void gemm_body(
    unsigned short* As, unsigned short* Bs,
    const unsigned short* __restrict__ A, int lda,
    const unsigned short* __restrict__ BT, int ldb,
    void* __restrict__ Cout, int ldc, int Kdim, int flags,
    const float* __restrict__ bias, int row0, int col0)
{
    int tid = threadIdx.x;
    int lane = tid & 63;
    int wave = tid >> 6;
    int mr = (wave & 1) * 64;
    int nc = (wave >> 1) * 64;
    int lr = lane & 15;
    int quad = lane >> 4;
    int swz = (lr & 7) << 3;          // fragment row&7 == lr&7

    f32x4 acc[4][4];
    #pragma unroll
    for (int i = 0; i < 4; i++)
        #pragma unroll
        for (int j = 0; j < 4; j++) acc[i][j] = (f32x4)0.0f;

    const int NKi = Kdim >> 6;
    // prologue: stage k=0 into buffer 0 (waited inside the loop's vmcnt)
    stage_tiles(As, Bs, A, lda, BT, ldb, row0, col0, 0);

    for (int k = 0; k < NKi; k++) {
        unsigned short* cA = As + (k & 1) * ASZ;
        unsigned short* cB = Bs + (k & 1) * ASZ;
        // issue next-tile DMA first, then wait ONLY for tile k (counted):
        // vmcnt retires in issue order, so vmcnt(8) with 16 outstanding
        // waits exactly for stage(k); stage(k+1) stays in flight.
        if (k + 1 < NKi) {
            stage_tiles(As + ((k + 1) & 1) * ASZ, Bs + ((k + 1) & 1) * ASZ,
                        A, lda, BT, ldb, row0, col0, (k + 1) * BKK);
            asm volatile("s_waitcnt vmcnt(8)" ::: "memory");
        } else {
            asm volatile("s_waitcnt vmcnt(0)" ::: "memory");
        }
        __builtin_amdgcn_s_barrier();   // all waves' tile-k DMA arrived

        #pragma unroll
        for (int ks = 0; ks < 2; ks++) {
            bf16x8 af[4], bfr[4];
            #pragma unroll
            for (int i = 0; i < 4; i++)
                af[i] = *(const bf16x8*)
                    &cA[(mr + i*16 + lr) * BKK + ((ks*32 + quad*8) ^ swz)];
            #pragma unroll
            for (int j = 0; j < 4; j++)
                bfr[j] = *(const bf16x8*)
                    &cB[(nc + j*16 + lr) * BKK + ((ks*32 + quad*8) ^ swz)];
            #pragma unroll
            for (int i = 0; i < 4; i++)
                #pragma unroll
                for (int j = 0; j < 4; j++)
                    acc[i][j] = __builtin_amdgcn_mfma_f32_16x16x32_bf16(
                        af[i], bfr[j], acc[i][j], 0, 0, 0);
        }
        // all my LDS reads of buf k retired; barrier so no wave's stage(k+2)
        // (issued next iteration) can overwrite buf k early.
        asm volatile("s_waitcnt lgkmcnt(0)" ::: "memory");
        __builtin_amdgcn_s_barrier();
    }

    float bvj[4];
    if (flags & 4) {
        #pragma unroll
        for (int j = 0; j < 4; j++) bvj[j] = bias[col0 + nc + j*16 + lr];
    } else {
        #pragma unroll
        for (int j = 0; j < 4; j++) bvj[j] = 0.0f;
    }

    if (flags & 1) {
        // V^T store: vbt[((b*8+h)*128 + d) * NT + t], 4 consecutive t packed
        unsigned short* V = (unsigned short*)Cout;
        #pragma unroll
        for (int i = 0; i < 4; i++) {
            int grow0 = row0 + mr + i*16 + quad*4;
            int bb = grow0 >> 10, tt = grow0 & 1023;
            #pragma unroll
            for (int j = 0; j < 4; j++) {
                int gcol = col0 + nc + j*16 + lr;
                int hh = gcol >> 7, dd = gcol & 127;
                ushort4 pk;
                pk.x = f2bf(acc[i][j][0]); pk.y = f2bf(acc[i][j][1]);
                pk.z = f2bf(acc[i][j][2]); pk.w = f2bf(acc[i][j][3]);
                *(ushort4*)(V + (((size_t)(bb*NH + hh)*HD + dd) * NT + tt)) = pk;
            }
        }
    } else if (flags & 2) {
        float* Cf = (float*)Cout;
        #pragma unroll
        for (int i = 0; i < 4; i++) {
            int grow0 = row0 + mr + i*16 + quad*4;
            #pragma unroll
            for (int j = 0; j < 4; j++) {
                int gcol = col0 + nc + j*16 + lr;
                #pragma unroll
                for (int r = 0; r < 4; r++) {
                    float v = acc[i][j][r] + bvj[j];
                    atomicAdd(&Cf[(size_t)(grow0 + r) * ldc + gcol], v);
                }
            }
        }
    } else {
        unsigned short* Cb = (unsigned short*)Cout;
        #pragma unroll
        for (int i = 0; i < 4; i++) {
            int grow0 = row0 + mr + i*16 + quad*4;
            #pragma unroll
            for (int j = 0; j < 4; j++) {
                int gcol = col0 + nc + j*16 + lr;
                #pragma unroll
                for (int r = 0; r < 4; r++) {
                    float v = acc[i][j][r] + bvj[j];
                    if (flags & 8) v = fmaxf(v, 0.0f);
                    Cb[(size_t)(grow0 + r) * ldc + gcol] = f2bf(v);
                }
            }
        }
    }
}

// Generic GEMM with K-split over blockIdx.z (Kper = K per split).
__global__ __launch_bounds__(256) void gemm_bf16(
    const unsigned short* __restrict__ A, int lda,
    const unsigned short* __restrict__ BT, int ldb,
    void* __restrict__ Cout, int ldc, int Kper, int flags,
    const float* __restrict__ bias)
{
    __shared__ unsigned short As[2 * ASZ];
    __shared__ unsigned short Bs[2 * ASZ];
    int row0 = blockIdx.y * 128, col0 = blockIdx.x * 128;
    int kbase = blockIdx.z * Kper;
    if (blockIdx.z) flags &= ~4;      // bias only once
    gemm_body(As, Bs, A + kbase, lda, BT + kbase, ldb, Cout, ldc,
              Kper, flags, bias, row0, col0);
}

// Fused Q/K/V projection: blockIdx.x in [0,24): weight = x>>3, col = (x&7)*128.
// Q uses Aq, K/V use Akv. V output goes to V^T layout.
__global__ __launch_bounds__(256) void gemm_qkv(
    const unsigned short* __restrict__ Aq,
    const unsigned short* __restrict__ Akv,
    const unsigned short* __restrict__ BTq,
    const unsigned short* __restrict__ BTk,
    const unsigned short* __restrict__ BTv,
    unsigned short* __restrict__ qb,
    unsigned short* __restrict__ kb,
    unsigned short* __restrict__ vbt)
{
    __shared__ unsigned short As[2 * ASZ];
    __shared__ unsigned short Bs[2 * ASZ];
    int w = blockIdx.x >> 3;
    int col0 = (blockIdx.x & 7) * 128;
    int row0 = blockIdx.y * 128;
    const unsigned short* A  = (w == 0) ? Aq : Akv;
    const unsigned short* BT = (w == 0) ? BTq : (w == 1) ? BTk : BTv;
    void* C  = (w == 0) ? (void*)qb : (w == 1) ? (void*)kb : (void*)vbt;
    int flags = (w == 2) ? 1 : 0;
    gemm_body(As, Bs, A, MD, BT, MD, C, MD, MD, flags, nullptr, row0, col0);
}

// ---------------------------------------------------------------------------
// MFMA flash attention v4: DMA double-buffer (zero-VGPR staging). Verified
// in R4/R6 (attn out of top-5). Unchanged this round (attribution).
// ---------------------------------------------------------------------------
#define KVB 64

__device__ __forceinline__ void stage_kv(
    unsigned short* KsB, unsigned short* VsB,
    const unsigned short* __restrict__ kbase,
    const unsigned short* __restrict__ vbase, int t0)
{
    int tid = threadIdx.x;
    #pragma unroll
    for (int it = 0; it < 4; it++) {
        int idx = it * 256 + tid;
        int r = idx >> 4, c8 = (idx & 15) ^ (r & 7);   // pre-swizzled source col
        load16_lds(kbase + (size_t)(t0 + r) * MD + c8 * 8, &KsB[idx * 8]);
    }
    #pragma unroll
    for (int it = 0; it < 4; it++) {
        int idx = it * 256 + tid;
        int r = idx >> 3, c8 = (idx & 7) ^ (r & 7);
        load16_lds(vbase + (size_t)r * NT + t0 + c8 * 8, &VsB[idx * 8]);
    }
}

__global__ __launch_bounds__(256) void attn_mfma(
    const unsigned short* __restrict__ qb, const unsigned short* __restrict__ kb,
    const unsigned short* __restrict__ vbt, unsigned short* __restrict__ pr,
    int causal)
{
    __shared__ unsigned short Ks[2][64 * 128];    // [key][d], swizzled
    __shared__ unsigned short Vs[2][128 * 64];    // [d][key], swizzled
    __shared__ unsigned short Ps[4 * 16 * 64];    // per-wave [qrow][key], swizzled

    int tid = threadIdx.x;
    int lane = tid & 63, wave = tid >> 6;
    int lr = lane & 15, quad = lane >> 4;

    int qt, bh;
    if (causal) {
        int bid = blockIdx.x + 16 * blockIdx.y;   // dispatch order, x fastest
        int half = bid >> 8, j = bid & 255;
        qt = half ? (15 - (j & 15)) : (j & 15);
        bh = (half << 4) | (j >> 4);
    } else {
        qt = blockIdx.x; bh = blockIdx.y;
    }
    int b = bh >> 3, h = bh & 7;
    int q0 = qt * 64;
    const float scale = 0.08838834764831845f;  // 1/sqrt(128)

    const unsigned short* kbase = kb + (size_t)(b * NT) * MD + h * HD;
    const unsigned short* vbase = vbt + (size_t)((b * NH + h) * HD) * NT;

    // ---- Q fragments: per-lane direct global load (one-time, L2-hot) ----
    const unsigned short* qrow_p =
        qb + (size_t)(b*NQ + q0 + wave*16 + lr) * MD + h*HD;
    bf16x8 aq[4];
    #pragma unroll
    for (int dk = 0; dk < 4; dk++)
        aq[dk] = *(const bf16x8*)(qrow_p + dk*32 + quad*8);

    // ---- prologue: DMA chunk 0 into buffer 0 ----
    stage_kv(Ks[0], Vs[0], kbase, vbase, 0);

    f32x4 acc[8];
    #pragma unroll
    for (int n = 0; n < 8; n++) acc[n] = (f32x4)0.0f;
    float m_run[4], l_run[4];
    #pragma unroll
    for (int r = 0; r < 4; r++) { m_run[r] = -1e30f; l_run[r] = 0.0f; }

    unsigned short* Pw = &Ps[wave * 16 * 64];
    int nch = causal ? (qt + 1) : (NT / KVB);
    int grow_base = q0 + wave*16 + quad*4;
    int swz = (lr & 7) << 3;   // XOR for rows where (row&7)==(lr&7)

    __syncthreads();           // drains chunk-0 DMA (vmcnt0 + barrier)

    for (int tc = 0; tc < nch; tc++) {
        int cur = tc & 1;
        // issue next-chunk DMA into the other buffer; it stays in flight
        // across the whole compute phase below.
        if (tc + 1 < nch)
            stage_kv(Ks[cur ^ 1], Vs[cur ^ 1], kbase, vbase, (tc + 1) * KVB);

        const unsigned short* Kc = Ks[cur];
        const unsigned short* Vc = Vs[cur];
        int t0 = tc * KVB;

        // ---- QK^T: 4 k-slices of 16 keys, K-dim 128 over 4 dk ----
        f32x4 s[4];
        #pragma unroll
        for (int kt = 0; kt < 4; kt++) s[kt] = (f32x4)0.0f;
        __builtin_amdgcn_s_setprio(1);
        #pragma unroll
        for (int dk = 0; dk < 4; dk++) {
            #pragma unroll
            for (int kt = 0; kt < 4; kt++) {
                bf16x8 bk = *(const bf16x8*)
                    &Kc[(kt*16 + lr) * 128 + ((dk*32 + quad*8) ^ swz)];
                s[kt] = __builtin_amdgcn_mfma_f32_16x16x32_bf16(aq[dk], bk, s[kt], 0, 0, 0);
            }
        }
        __builtin_amdgcn_s_setprio(0);

        // ---- online softmax over 64 keys, defer-max (T13) ----
        float mxt[4];
        #pragma unroll
        for (int r = 0; r < 4; r++) {
            #pragma unroll
            for (int kt = 0; kt < 4; kt++) {
                float x = s[kt][r] * scale;
                if (causal && (t0 + kt*16 + lr > grow_base + r)) x = -1e30f;
                s[kt][r] = x;
            }
            float mx = fmaxf(fmaxf(s[0][r], s[1][r]), fmaxf(s[2][r], s[3][r]));
            #pragma unroll
            for (int off = 1; off < 16; off <<= 1)
                mx = fmaxf(mx, __shfl_xor(mx, off));
            mxt[r] = mx;
        }
        float need = fmaxf(fmaxf(mxt[0]-m_run[0], mxt[1]-m_run[1]),
                           fmaxf(mxt[2]-m_run[2], mxt[3]-m_run[3]));
        if (!__all(need <= 8.0f)) {
            #pragma unroll
            for (int r = 0; r < 4; r++) {
                float mx = fmaxf(mxt[r], m_run[r]);
                float alpha = __expf(m_run[r] - mx);
                m_run[r] = mx;
                l_run[r] *= alpha;
                #pragma unroll
                for (int n = 0; n < 8; n++) acc[n][r] *= alpha;
            }
        }
        #pragma unroll
        for (int r = 0; r < 4; r++) {
            int prow = quad*4 + r;
            int pswz = (prow & 7) << 3;
            float psum = 0.0f;
            #pragma unroll
            for (int kt = 0; kt < 4; kt++) {
                float p = __expf(s[kt][r] - m_run[r]);
                Pw[prow * 64 + ((kt*16 + lr) ^ pswz)] = f2bf(p);
                psum += p;
            }
            #pragma unroll
            for (int off = 1; off < 16; off <<= 1)
                psum += __shfl_xor(psum, off);
            l_run[r] += psum;
        }

        // ---- PV: P (16x64) x V^T fragments ----
        bf16x8 ap0 = *(const bf16x8*)&Pw[lr * 64 + ((quad * 8) ^ swz)];
        bf16x8 ap1 = *(const bf16x8*)&Pw[lr * 64 + ((32 + quad * 8) ^ swz)];
        __builtin_amdgcn_s_setprio(1);
        #pragma unroll
        for (int n = 0; n < 8; n++) {
            bf16x8 bv0 = *(const bf16x8*)
                &Vc[(n*16 + lr) * 64 + ((quad * 8) ^ swz)];
            bf16x8 bv1 = *(const bf16x8*)
                &Vc[(n*16 + lr) * 64 + ((32 + quad * 8) ^ swz)];
            acc[n] = __builtin_amdgcn_mfma_f32_16x16x32_bf16(ap0, bv0, acc[n], 0, 0, 0);
            acc[n] = __builtin_amdgcn_mfma_f32_16x16x32_bf16(ap1, bv1, acc[n], 0, 0, 0);
        }
        __builtin_amdgcn_s_setprio(0);

        // one barrier per chunk: all waves done reading buffers (lgkm) AND
        // the next chunk's DMA drained (vmcnt) -- it had the compute in flight.
        __syncthreads();
    }

    float linv[4];
    #pragma unroll
    for (int r = 0; r < 4; r++) linv[r] = 1.0f / l_run[r];
    #pragma unroll
    for (int n = 0; n < 8; n++) {
        int gcol = h*HD + n*16 + lr;
        #pragma unroll
        for (int r = 0; r < 4; r++) {
            int grow = q0 + wave*16 + quad*4 + r;
            pr[(size_t)(b*NQ + grow) * MD + gcol] = f2bf(acc[n][r] * linv[r]);
        }
    }
}

// ---------------------------------------------------------------------------
extern "C" void kernel_launch(void* const* d_in, const int* in_sizes, int n_in,
                              void* d_out, int out_size, void* d_ws, size_t ws_size,
                              hipStream_t stream)
{
    const float* enc  = (const float*)d_in[0];
    const float* x    = (const float*)d_in[1];
    const float* swq  = (const float*)d_in[5];
    const float* swk  = (const float*)d_in[6];
    const float* swv  = (const float*)d_in[7];
    const float* swo  = (const float*)d_in[8];
    const float* cwq  = (const float*)d_in[9];
    const float* cwk  = (const float*)d_in[10];
    const float* cwv  = (const float*)d_in[11];
    const float* cwo  = (const float*)d_in[12];
    const float* w1   = (const float*)d_in[13];
    const float* b1   = (const float*)d_in[14];
    const float* w2   = (const float*)d_in[15];
    const float* b2   = (const float*)d_in[16];
    const float* ln1g = (const float*)d_in[17];
    const float* ln1b = (const float*)d_in[18];
    const float* ln2g = (const float*)d_in[19];
    const float* ln2b = (const float*)d_in[20];
    const float* ln3g = (const float*)d_in[21];
    const float* ln3b = (const float*)d_in[22];

    float* h = (float*)d_out;
    unsigned short* u = (unsigned short*)d_ws;
    const size_t MW = 1024 * 1024;
    unsigned short* nb   = u;             // 4M ushort
    unsigned short* encb = u + 4*MW;      // 4M
    unsigned short* qb   = u + 8*MW;      // 4M
    unsigned short* kb   = u + 12*MW;     // 4M
    unsigned short* vbt  = u + 16*MW;     // 4M
    unsigned short* pr   = u + 20*MW;     // 4M
    unsigned short* sb   = qb;            // aliases qb..pr (16M), FFN-only
    unsigned short* wb   = u + 24*MW;

    bool upfront = ws_size >= (size_t)240 * MW;

    hipMemcpyAsync(h, x, 4*MW*sizeof(float), hipMemcpyDeviceToDevice, stream);

    dim3 tb(256);
    cast_bf16<<<4096, tb, 0, stream>>>(enc, encb);

    if (upfront) {
        transpose_cast<<<dim3(4,32,48),  tb, 0, stream>>>(swq, wb + 0*MW,  1024, 128);
        transpose_cast<<<dim3(4,32,48),  tb, 0, stream>>>(swk, wb + 6*MW,  1024, 128);
        transpose_cast<<<dim3(4,32,48),  tb, 0, stream>>>(swv, wb + 12*MW, 1024, 128);
        transpose_cast<<<dim3(32,32,6),  tb, 0, stream>>>(swo, wb + 18*MW, 1024, 1024);
        transpose_cast<<<dim3(4,32,48),  tb, 0, stream>>>(cwq, wb + 24*MW, 1024, 128);
        transpose_cast<<<dim3(4,32,48),  tb, 0, stream>>>(cwk, wb + 30*MW, 1024, 128);
        transpose_cast<<<dim3(4,32,48),  tb, 0, stream>>>(cwv, wb + 36*MW, 1024, 128);
        transpose_cast<<<dim3(32,32,6),  tb, 0, stream>>>(cwo, wb + 42*MW, 1024, 1024);
        transpose_cast<<<dim3(128,32,6), tb, 0, stream>>>(w1,  wb + 48*MW, 1024, 4096);
        transpose_cast<<<dim3(32,128,6), tb, 0, stream>>>(w2,  wb + 72*MW, 4096, 1024);
    }

    dim3 gQKV(24, 32), gO(8, 32, 2), gF1(32, 32), gF2(8, 32, 2), gA(16, 32);

    for (int l = 0; l < NL; l++) {
        unsigned short *pwq, *pwk, *pwv, *pwo, *pcq, *pck, *pcv, *pco, *pw1, *pw2;
        if (upfront) {
            pwq = wb + 0*MW  + l*MW;  pwk = wb + 6*MW  + l*MW;
            pwv = wb + 12*MW + l*MW;  pwo = wb + 18*MW + l*MW;
            pcq = wb + 24*MW + l*MW;  pck = wb + 30*MW + l*MW;
            pcv = wb + 36*MW + l*MW;  pco = wb + 42*MW + l*MW;
            pw1 = wb + 48*MW + l*4*MW; pw2 = wb + 72*MW + l*4*MW;
        } else {
            pwq = wb;        pwk = wb + 1*MW; pwv = wb + 2*MW; pwo = wb + 3*MW;
            pcq = wb + 4*MW; pck = wb + 5*MW; pcv = wb + 6*MW; pco = wb + 7*MW;
            pw1 = wb + 8*MW; pw2 = wb + 12*MW;
            transpose_cast<<<dim3(4,32,8),   tb, 0, stream>>>(swq + l*MW,   pwq, 1024, 128);
            transpose_cast<<<dim3(4,32,8),   tb, 0, stream>>>(swk + l*MW,   pwk, 1024, 128);
            transpose_cast<<<dim3(4,32,8),   tb, 0, stream>>>(swv + l*MW,   pwv, 1024, 128);
            transpose_cast<<<dim3(32,32,1),  tb, 0, stream>>>(swo + l*MW,   pwo, 1024, 1024);
            transpose_cast<<<dim3(4,32,8),   tb, 0, stream>>>(cwq + l*MW,   pcq, 1024, 128);
            transpose_cast<<<dim3(4,32,8),   tb, 0, stream>>>(cwk + l*MW,   pck, 1024, 128);
            transpose_cast<<<dim3(4,32,8),   tb, 0, stream>>>(cwv + l*MW,   pcv, 1024, 128);
            transpose_cast<<<dim3(32,32,1),  tb, 0, stream>>>(cwo + l*MW,   pco, 1024, 1024);
            transpose_cast<<<dim3(128,32,1), tb, 0, stream>>>(w1 + l*4*MW,  pw1, 1024, 4096);
            transpose_cast<<<dim3(32,128,1), tb, 0, stream>>>(w2 + l*4*MW,  pw2, 4096, 1024);
        }

        // ---- self attention ----
        ln_kernel<<<ROWS, tb, 0, stream>>>(h, nb, ln1g + l*MD, ln1b + l*MD);
        gemm_qkv<<<gQKV, tb, 0, stream>>>(nb, nb, pwq, pwk, pwv, qb, kb, vbt);
        attn_mfma<<<gA, tb, 0, stream>>>(qb, kb, vbt, pr, 1);
        gemm_bf16<<<gO, tb, 0, stream>>>(pr, MD, pwo, MD, h, MD, 512, 2, nullptr);

        // ---- cross attention ----
        ln_kernel<<<ROWS, tb, 0, stream>>>(h, nb, ln2g + l*MD, ln2b + l*MD);
        gemm_qkv<<<gQKV, tb, 0, stream>>>(nb, encb, pcq, pck, pcv, qb, kb, vbt);
        attn_mfma<<<gA, tb, 0, stream>>>(qb, kb, vbt, pr, 0);
        gemm_bf16<<<gO, tb, 0, stream>>>(pr, MD, pco, MD, h, MD, 512, 2, nullptr);

        // ---- FFN ----
        ln_kernel<<<ROWS, tb, 0, stream>>>(h, nb, ln3g + l*MD, ln3b + l*MD);
        gemm_bf16<<<gF1, tb, 0, stream>>>(nb, MD, pw1, MD, sb, FF, 1024, 4 | 8, b1 + l*FF);
        gemm_bf16<<<gF2, tb, 0, stream>>>(sb, FF, pw2, FF, h, MD, 2048, 2 | 4, b2 + l*MD);
    }
}